// Round 8
// baseline (1796.028 us; speedup 1.0000x reference)
//
#include <hip/hip_runtime.h>
#include <hip/hip_bf16.h>

// SPINN: word GEMM + XCD-sharded persistent TreeLSTM (fence-free level sync).
// Trees sharded by batch&7 onto physical XCDs => all inter-level data flow is
// intra-XCD (shared L2 = coherence point, no wbl2/inv needed).
// r8: 4 blocks/CU (1024 blocks) + fixed u-block per block (cross-level L2 reuse).
// B=128, L=64, E=512, H=512, T=127.

#define Bn 128
#define Ln 64
#define En 512
#define Hn 512
#define Tn 127
#define LEAF_ROWS (Bn*Ln)        // 8192 word rows
#define NODE_ROWS (Bn*(Ln-1))    // 8064 reduce-node rows
#define TOT_ROWS (LEAF_ROWS+NODE_ROWS)
#define NLVL 64
#define NXCD 8
#define CAPX 512                 // max rows per XCD-bin per level (16 trees * 32)
#define GATE_STRIDE (512*1024)   // WT element stride between gates
#define NBLK 1024                // persistent grid (4 blocks/CU => exactly fills chip)
#define FPAD 16                  // flag padding (one per 64B line)
#define MAXRANK 256
#define SPIN_CAP (1<<22)

// barrier/census state layout (ints), zeroed by precompute_ctrl each call
#define OFF_CENSUS 0                              // NXCD*FPAD
#define OFF_SFLAG  (OFF_CENSUS + NXCD*FPAD)       // NBLK*FPAD
#define OFF_SGEN   (OFF_SFLAG + NBLK*FPAD)        // FPAD
#define OFF_FX     (OFF_SGEN + FPAD)              // NXCD*MAXRANK*FPAD
#define OFF_GX     (OFF_FX + NXCD*MAXRANK*FPAD)   // NXCD*FPAD
#define BAR_INTS   (OFF_GX + NXCD*FPAD)

typedef __attribute__((ext_vector_type(8))) short bf16x8;
typedef __attribute__((ext_vector_type(4))) float f32x4;

static __device__ __forceinline__ float bf2f(unsigned short u){
  unsigned v = ((unsigned)u) << 16;
  float f; __builtin_memcpy(&f, &v, 4); return f;
}
static __device__ __forceinline__ unsigned short f2bf(float f){
  unsigned u; __builtin_memcpy(&u, &f, 4);
  u = u + 0x7FFFu + ((u >> 16) & 1u);   // round-nearest-even
  return (unsigned short)(u >> 16);
}
static __device__ __forceinline__ float sigm(float x){
  return 1.0f / (1.0f + __expf(-x));
}
static __device__ __forceinline__ float tanh_fast(float x){
  x = fminf(fmaxf(x, -15.0f), 15.0f);
  float t = __expf(2.0f * x);
  return (t - 1.0f) / (t + 1.0f);
}
static __device__ __forceinline__ int xcc_id(){
  unsigned v;
  asm volatile("s_getreg_b32 %0, hwreg(HW_REG_XCC_ID)" : "=s"(v));
  return (int)(v & 7);
}

// Per-XCD fence-free barrier among the nx blocks resident on XCD x.
// Data coherence: producers' stores reach the shared XCD L2 via the vmcnt(0)
// drain in __syncthreads; consumers first-touch-load via the same L2. Flags use
// relaxed agent-scope atomics purely for arrival signaling.
static __device__ __forceinline__ void xcd_barrier(int* bar, int x, int rank, int nx, int epoch){
  __syncthreads();
  int* fx = bar + OFF_FX + x * MAXRANK * FPAD;
  int* gx = bar + OFF_GX + x * FPAD;
  int nxl = min(nx, MAXRANK);
  if (rank == 0){
    for (int i = threadIdx.x + 1; i < nxl; i += 256){
      int c = 0;
      while (__hip_atomic_load(&fx[i * FPAD], __ATOMIC_RELAXED, __HIP_MEMORY_SCOPE_AGENT) < epoch && c < SPIN_CAP){
        __builtin_amdgcn_s_sleep(1); ++c;
      }
    }
    __syncthreads();
    if (threadIdx.x == 0)
      __hip_atomic_store(gx, epoch, __ATOMIC_RELAXED, __HIP_MEMORY_SCOPE_AGENT);
  } else {
    if (threadIdx.x == 0){
      __hip_atomic_store(&fx[rank * FPAD], epoch, __ATOMIC_RELAXED, __HIP_MEMORY_SCOPE_AGENT);
      int c = 0;
      while (__hip_atomic_load(gx, __ATOMIC_RELAXED, __HIP_MEMORY_SCOPE_AGENT) < epoch && c < SPIN_CAP){
        __builtin_amdgcn_s_sleep(2); ++c;
      }
    }
    __syncthreads();
  }
  asm volatile("" ::: "memory");
}

// ---------------- convert / transpose helpers ----------------

__global__ void cvt_vec4(const float4* __restrict__ x, ushort4* __restrict__ y, int n4){
  int i = blockIdx.x * 256 + threadIdx.x;
  if (i < n4){
    float4 v = x[i];
    ushort4 o;
    o.x = f2bf(v.x); o.y = f2bf(v.y); o.z = f2bf(v.z); o.w = f2bf(v.w);
    y[i] = o;
  }
}

// dstT[c*DS + koff + r] = bf16(src[r*CS + c]); tiles 32x32, block (32,8)
__global__ void transpose_cvt(const float* __restrict__ src, unsigned short* __restrict__ dstT,
                              int CS, int DS, int koff){
  __shared__ float tile[32][33];
  int c0 = blockIdx.x * 32, r0 = blockIdx.y * 32;
  int tx = threadIdx.x, ty = threadIdx.y;
  for (int i = ty; i < 32; i += 8) tile[i][tx] = src[(size_t)(r0 + i) * CS + c0 + tx];
  __syncthreads();
  for (int i = ty; i < 32; i += 8)
    dstT[(size_t)(c0 + i) * DS + koff + r0 + tx] = f2bf(tile[tx][i]);
}

// ---------------- control precompute: stack sim -> per-(XCD,level) dataflow ----------------
__global__ void precompute_ctrl(const int* __restrict__ trans,
                                int* __restrict__ srcL, int* __restrict__ srcR,
                                int* __restrict__ dstv, int* __restrict__ cnt,
                                int* __restrict__ outsrc, int* __restrict__ bar){
  __shared__ int stk[Bn][Ln + 1];    // padded
  __shared__ int scnt[NXCD * NLVL];
  __shared__ int smaxl[NXCD];
  int b = threadIdx.x;
  for (int i = b; i < NXCD * NLVL; i += 128) scnt[i] = 0;
  if (b < NXCD) smaxl[b] = 0;
  for (int i = b; i < BAR_INTS; i += 128) bar[i] = 0;
  __syncthreads();
  int x = b & 7;
  int sp = 0, bp = 0, nodecnt = 0;
  int act_next = trans[b * Tn];
  for (int t = 0; t < Tn; t++){
    int act = act_next;
    if (t + 1 < Tn) act_next = trans[b * Tn + t + 1];
    int ops = Tn - t;
    if (sp > ops) act = 2;                       // forced REDUCE (matches ref)
    if (act == 2){                               // REDUCE
      int R = stk[b][sp - 1], L = stk[b][sp - 2];
      int lvl = max(R >> 20, L >> 20) + 1;       // 1..63
      int slot = atomicAdd(&scnt[x * NLVL + lvl], 1);
      int base = (x * NLVL + lvl) * CAPX + slot;
      srcL[base] = (L & 0xFFFFF) * Hn;
      srcR[base] = (R & 0xFFFFF) * Hn;
      int noderow = LEAF_ROWS + b * (Ln - 1) + nodecnt;
      dstv[base] = noderow * Hn;
      stk[b][sp - 2] = noderow | (lvl << 20);
      sp -= 1; nodecnt++;
    } else {                                     // SHIFT (leaf: level 0)
      stk[b][sp] = b * Ln + min(bp, Ln - 1);
      sp += 1; bp += 1;
    }
  }
  int root = stk[b][max(sp - 1, 0)];
  outsrc[b] = (root & 0xFFFFF) * Hn;
  atomicMax(&smaxl[x], root >> 20);
  __syncthreads();
  for (int i = b; i < NXCD * NLVL; i += 128) cnt[i] = scnt[i];
  if (b < NXCD) cnt[NXCD * NLVL + b] = smaxl[b];
}

// ---------------- word GEMM: out = sentence @ W_word + b_word ----------------
__global__ __launch_bounds__(256) void word_gemm(
    const unsigned short* __restrict__ SB, const unsigned short* __restrict__ WwT,
    const float* __restrict__ b_word,
    unsigned short* __restrict__ HB, float* __restrict__ CF){
  int nt = blockIdx.x;            // 8 N-tiles (XCD-affine)
  int mt = blockIdx.y;            // 128 M-tiles
  int tid = threadIdx.x, w = tid >> 6, lane = tid & 63;
  int wm = w >> 1, wn = w & 1;
  int rc = lane & 15, lg = lane >> 4;
  const unsigned short* ap0 = SB + (size_t)(mt * 64 + wm * 32 + rc) * En + lg * 8;
  const unsigned short* ap1 = ap0 + (size_t)16 * En;
  const unsigned short* bp0 = WwT + (size_t)(nt * 128 + wn * 64 + rc) * En + lg * 8;
  f32x4 acc[2][4];
  #pragma unroll
  for (int h = 0; h < 2; h++)
    #pragma unroll
    for (int nb = 0; nb < 4; nb++) acc[h][nb] = (f32x4){0.f,0.f,0.f,0.f};
  #pragma unroll 4
  for (int k0 = 0; k0 < En; k0 += 32){
    bf16x8 a0 = *(const bf16x8*)(ap0 + k0);
    bf16x8 a1 = *(const bf16x8*)(ap1 + k0);
    #pragma unroll
    for (int nb = 0; nb < 4; nb++){
      bf16x8 bb = *(const bf16x8*)(bp0 + (size_t)nb * 16 * En + k0);
      acc[0][nb] = __builtin_amdgcn_mfma_f32_16x16x32_bf16(a0, bb, acc[0][nb], 0, 0, 0);
      acc[1][nb] = __builtin_amdgcn_mfma_f32_16x16x32_bf16(a1, bb, acc[1][nb], 0, 0, 0);
    }
  }
  #pragma unroll
  for (int nb = 0; nb < 4; nb++){
    int col = nt * 128 + wn * 64 + nb * 16 + rc;
    float bw = b_word[col];
    #pragma unroll
    for (int h = 0; h < 2; h++){
      #pragma unroll
      for (int q = 0; q < 4; q++){
        int row = mt * 64 + wm * 32 + h * 16 + lg * 4 + q;
        float v = acc[h][nb][q] + bw;
        if (col < Hn) HB[(size_t)row * Hn + col] = f2bf(v);
        else          CF[(size_t)row * Hn + (col - Hn)] = v;
      }
    }
  }
}

// ---------------- one 16u x MB-row tile ----------------
template<int MR>
static __device__ __forceinline__ void process_tile(
    int ub, int tile, int nr, const int* sL, const int* sR, const int* dl,
    unsigned short* __restrict__ HB, float* __restrict__ CF,
    const unsigned short* __restrict__ WT, const float* __restrict__ b_red,
    float (*part)[5][16][20],
    int w, int rc, int lg, int khalf, int kq, int er, int eu)
{
  const int MB = 16 * MR;
  int u0 = ub * 16;
  const unsigned short* bbase = WT + (size_t)(u0 + rc) * 1024 + khalf * 512 + kq * 256 + lg * 8;
  int base = tile * MB;
  int offA[MR];
  #pragma unroll
  for (int m = 0; m < MR; m++){
    int i = min(base + m * 16 + rc, nr - 1);
    offA[m] = (khalf ? sR : sL)[i];
  }
  f32x4 acc[5][MR];
  #pragma unroll
  for (int g = 0; g < 5; g++)
    #pragma unroll
    for (int m = 0; m < MR; m++) acc[g][m] = (f32x4){0.f,0.f,0.f,0.f};
  #pragma unroll
  for (int j = 0; j < 8; ++j){
    bf16x8 a[MR];
    #pragma unroll
    for (int m = 0; m < MR; m++)
      a[m] = *(const bf16x8*)(HB + offA[m] + kq * 256 + lg * 8 + j * 32);
    #pragma unroll
    for (int g = 0; g < 5; g++){
      bf16x8 bb = *(const bf16x8*)(bbase + (size_t)g * GATE_STRIDE + j * 32);
      #pragma unroll
      for (int m = 0; m < MR; m++)
        acc[g][m] = __builtin_amdgcn_mfma_f32_16x16x32_bf16(a[m], bb, acc[g][m], 0, 0, 0);
    }
  }
  int colu = u0 + eu;
  float bg  = b_red[colu];
  float bi  = b_red[Hn + colu];
  float bf1 = b_red[2 * Hn + colu];
  float bf2 = b_red[3 * Hn + colu];
  float bo  = b_red[4 * Hn + colu];
  #pragma unroll
  for (int m = 0; m < MR; m++){
    #pragma unroll
    for (int q = 0; q < 4; ++q){
      int r = lg * 4 + q;                      // C/D: row=(lane>>4)*4+q, col=lane&15
      #pragma unroll
      for (int g = 0; g < 5; g++) part[w][g][r][rc] = acc[g][m][q];
    }
    __syncthreads();
    int i = base + m * 16 + er;
    if (i < nr){
      float s[5];
      #pragma unroll
      for (int g = 0; g < 5; g++)
        s[g] = part[0][g][er][eu] + part[1][g][er][eu] + part[2][g][er][eu] + part[3][g][er][eu];
      float gv  = tanh_fast(s[0] + bg);
      float iv  = sigm(s[1] + bi);
      float f1v = sigm(s[2] + bf1);
      float f2v = sigm(s[3] + bf2);
      float ov  = sigm(s[4] + bo);
      int oL = sL[i], oR = sR[i], oD = dl[i];
      float cl = CF[oL + colu], cr = CF[oR + colu];
      float cv = gv * iv + f1v * cl + f2v * cr;
      float hv = ov * tanh_fast(cv);
      CF[oD + colu] = cv;
      HB[oD + colu] = f2bf(hv);
    }
    __syncthreads();
  }
}

// ---------------- per-level tile scheduler ----------------
// nx >= 32: FIXED u-block per block (ub = rank&31) so each block re-reads the
// same 160KB weight slice every level -> cross-level L2 residency; row tiles
// striped over the (nx/32) blocks sharing each ub. Fallback: flat interleave.
template<int MR>
static __device__ __forceinline__ void tiles_x(
    int nr, int rank, int nx, const int* sL, const int* sR, const int* dl,
    unsigned short* __restrict__ HB, float* __restrict__ CF,
    const unsigned short* __restrict__ WT, const float* __restrict__ b_red,
    float (*part)[5][16][20],
    int w, int rc, int lg, int khalf, int kq, int er, int eu)
{
  const int MB = 16 * MR;
  int ntl = (nr + MB - 1) / MB;
  if (nx >= 32){
    int ub = rank & 31, stripe = rank >> 5;
    int nstr = (nx - 1 - ub) / 32 + 1;           // blocks sharing this ub
    for (int tile = stripe; tile < ntl; tile += nstr)
      process_tile<MR>(ub, tile, nr, sL, sR, dl, HB, CF, WT, b_red, part, w, rc, lg, khalf, kq, er, eu);
  } else {
    int ntasks = ntl * 32;
    for (int task = rank; task < ntasks; task += nx)
      process_tile<MR>(task / ntl, task % ntl, nr, sL, sR, dl, HB, CF, WT, b_red, part, w, rc, lg, khalf, kq, er, eu);
  }
}

// ---------------- persistent XCD-sharded tree kernel ----------------
// 1024 blocks (4/CU, chip-exact). Census: each block gets (xcd, rank). XCD x
// processes trees {b : b&7==x} level by level with fence-free local barriers.
__global__ __launch_bounds__(256, 4) void tree_kernel(
    unsigned short* __restrict__ HB, float* __restrict__ CF,
    const unsigned short* __restrict__ WT, const float* __restrict__ b_red,
    const int* __restrict__ srcL, const int* __restrict__ srcR,
    const int* __restrict__ dstv, const int* __restrict__ cnt,
    const int* __restrict__ outsrc, float* __restrict__ out, int* bar){
  __shared__ float part[4][5][16][20];   // [wave][gate][row][col(+pad)]
  __shared__ int s_tmp[2];
  int bid = blockIdx.x;
  int tid = threadIdx.x, w = tid >> 6, lane = tid & 63;
  int rc = lane & 15, lg = lane >> 4;
  int er = tid >> 4, eu = tid & 15;
  int khalf = w >> 1, kq = w & 1;

  int x = xcc_id();
  if (tid == 0)
    s_tmp[0] = __hip_atomic_fetch_add(&bar[OFF_CENSUS + x * FPAD], 1,
                                      __ATOMIC_RELAXED, __HIP_MEMORY_SCOPE_AGENT);
  __syncthreads();
  int rank = min(s_tmp[0], MAXRANK - 1);

  // one global start barrier so census counts are final
  {
    int* sfl  = bar + OFF_SFLAG;
    int* sgen = bar + OFF_SGEN;
    if (bid == 0){
      for (int i = tid; i < NBLK; i += 256){
        if (i){
          int c = 0;
          while (__hip_atomic_load(&sfl[i * FPAD], __ATOMIC_RELAXED, __HIP_MEMORY_SCOPE_AGENT) == 0 && c < SPIN_CAP){
            __builtin_amdgcn_s_sleep(1); ++c;
          }
        }
      }
      __syncthreads();
      if (tid == 0) __hip_atomic_store(sgen, 1, __ATOMIC_RELAXED, __HIP_MEMORY_SCOPE_AGENT);
    } else {
      if (tid == 0){
        __hip_atomic_store(&sfl[bid * FPAD], 1, __ATOMIC_RELAXED, __HIP_MEMORY_SCOPE_AGENT);
        int c = 0;
        while (__hip_atomic_load(sgen, __ATOMIC_RELAXED, __HIP_MEMORY_SCOPE_AGENT) == 0 && c < SPIN_CAP){
          __builtin_amdgcn_s_sleep(2); ++c;
        }
      }
      __syncthreads();
    }
  }

  if (tid == 0)
    s_tmp[1] = __hip_atomic_load(&bar[OFF_CENSUS + x * FPAD], __ATOMIC_RELAXED, __HIP_MEMORY_SCOPE_AGENT);
  __syncthreads();
  int nx = max(s_tmp[1], 1);

  int maxlvl = cnt[NXCD * NLVL + x];
  int epoch = 1;
  for (int lvl = 1; lvl <= maxlvl; ++lvl, ++epoch){
    int nr = cnt[x * NLVL + lvl];
    const int* sL = srcL + (x * NLVL + lvl) * CAPX;
    const int* sR = srcR + (x * NLVL + lvl) * CAPX;
    const int* dl = dstv + (x * NLVL + lvl) * CAPX;
    if (nr > 0){
      if (nr >= 256)
        tiles_x<4>(nr, rank, nx, sL, sR, dl, HB, CF, WT, b_red, part, w, rc, lg, khalf, kq, er, eu);
      else if (nr >= 96)
        tiles_x<2>(nr, rank, nx, sL, sR, dl, HB, CF, WT, b_red, part, w, rc, lg, khalf, kq, er, eu);
      else
        tiles_x<1>(nr, rank, nx, sL, sR, dl, HB, CF, WT, b_red, part, w, rc, lg, khalf, kq, er, eu);
    }
    xcd_barrier(bar, x, rank, nx, epoch);
  }

  // final gather for this XCD's 16 trees: out[b][u] = f32(h_root[b][u])
  for (int j = rank; j < 16; j += min(nx, MAXRANK)){
    int b = x + 8 * j;
    int src = outsrc[b];
    out[b * Hn + tid]       = bf2f(HB[src + tid]);
    out[b * Hn + tid + 256] = bf2f(HB[src + tid + 256]);
  }
}

// ---------------- launch ----------------
extern "C" void kernel_launch(void* const* d_in, const int* in_sizes, int n_in,
                              void* d_out, int out_size, void* d_ws, size_t ws_size,
                              hipStream_t stream){
  (void)in_sizes; (void)n_in; (void)out_size; (void)ws_size;
  const float* sentence = (const float*)d_in[0];
  const int*   trans    = (const int*)d_in[1];
  const float* W_word   = (const float*)d_in[2];
  const float* b_word   = (const float*)d_in[3];
  const float* W_left   = (const float*)d_in[4];
  const float* W_right  = (const float*)d_in[5];
  const float* b_red    = (const float*)d_in[6];

  char* ws = (char*)d_ws;
  size_t off = 0;
  auto alloc = [&](size_t bytes) -> void* {
    void* p = ws + off;
    off += (bytes + 255) & ~((size_t)255);
    return p;
  };
  unsigned short* HB  = (unsigned short*)alloc((size_t)TOT_ROWS * Hn * 2); // bf16 h
  float*          CF  = (float*)alloc((size_t)TOT_ROWS * Hn * 4);          // f32 c
  unsigned short* WT  = (unsigned short*)alloc((size_t)2560 * 1024 * 2);   // [W_left;W_right]^T bf16
  unsigned short* SB  = (unsigned short*)alloc((size_t)LEAF_ROWS * En * 2);// sentence bf16
  unsigned short* WwT = (unsigned short*)alloc((size_t)1024 * En * 2);     // W_word^T bf16
  int* srcL   = (int*)alloc((size_t)NXCD * NLVL * CAPX * 4);
  int* srcR   = (int*)alloc((size_t)NXCD * NLVL * CAPX * 4);
  int* dstv   = (int*)alloc((size_t)NXCD * NLVL * CAPX * 4);
  int* cnt    = (int*)alloc((size_t)(NXCD * NLVL + NXCD) * 4);
  int* outsrc = (int*)alloc((size_t)Bn * 4);
  int* bar    = (int*)alloc((size_t)BAR_INTS * 4);
  float* outp = (float*)d_out;

  cvt_vec4<<<(LEAF_ROWS * En / 4) / 256, 256, 0, stream>>>((const float4*)sentence, (ushort4*)SB, LEAF_ROWS * En / 4);
  transpose_cvt<<<dim3(1024 / 32, En / 32), dim3(32, 8), 0, stream>>>(W_word, WwT, 1024, En, 0);
  transpose_cvt<<<dim3(2560 / 32, Hn / 32), dim3(32, 8), 0, stream>>>(W_left, WT, 2560, 1024, 0);
  transpose_cvt<<<dim3(2560 / 32, Hn / 32), dim3(32, 8), 0, stream>>>(W_right, WT, 2560, 1024, 512);
  precompute_ctrl<<<1, 128, 0, stream>>>(trans, srcL, srcR, dstv, cnt, outsrc, bar);
  word_gemm<<<dim3(8, LEAF_ROWS / 64), 256, 0, stream>>>(SB, WwT, b_word, HB, CF);
  tree_kernel<<<NBLK, 256, 0, stream>>>(HB, CF, WT, b_red, srcL, srcR, dstv, cnt, outsrc, outp, bar);
}

// Round 9
// 847.166 us; speedup vs baseline: 2.1200x; 2.1200x over previous
//
#include <hip/hip_runtime.h>
#include <hip/hip_bf16.h>

// SPINN: word GEMM + XCD-sharded persistent TreeLSTM with LDS-resident weights.
// 256 blocks (1/CU, 32/XCD). Block = one u-block (16 hidden units): its weight
// slice gates 0-3 (128KB) staged into LDS once (XOR-swizzled); gate 4 streamed
// from global (1MB/XCD -> L2-resident). Waves compute full-K 64-row tiles, all
// 5 gates in registers, lane-local LSTM epilogue (no LDS combine).
// B=128, L=64, E=512, H=512, T=127.

#define Bn 128
#define Ln 64
#define En 512
#define Hn 512
#define Tn 127
#define LEAF_ROWS (Bn*Ln)
#define NODE_ROWS (Bn*(Ln-1))
#define TOT_ROWS (LEAF_ROWS+NODE_ROWS)
#define NLVL 64
#define NXCD 8
#define CAPX 512                 // max rows per XCD-bin per level
#define NBLK 256                 // 1 block/CU
#define FPAD 16
#define MAXRANK 64
#define SPIN_CAP (1<<22)
#define WLDS_BYTES 131072        // 4 gates x 16u x 1024K x 2B

// barrier/census state layout (ints), zeroed by precompute_ctrl each call
#define OFF_CENSUS 0                              // NXCD*FPAD
#define OFF_RANK   (OFF_CENSUS + NXCD*FPAD)       // NBLK*FPAD
#define OFF_SFLAG  (OFF_RANK + NBLK*FPAD)         // NBLK*FPAD
#define OFF_SGEN   (OFF_SFLAG + NBLK*FPAD)        // FPAD
#define OFF_FX     (OFF_SGEN + FPAD)              // NXCD*MAXRANK*FPAD
#define OFF_GX     (OFF_FX + NXCD*MAXRANK*FPAD)   // NXCD*FPAD
#define BAR_INTS   (OFF_GX + NXCD*FPAD)

typedef __attribute__((ext_vector_type(8))) short bf16x8;
typedef __attribute__((ext_vector_type(4))) float f32x4;

static __device__ __forceinline__ float bf2f(unsigned short u){
  unsigned v = ((unsigned)u) << 16;
  float f; __builtin_memcpy(&f, &v, 4); return f;
}
static __device__ __forceinline__ unsigned short f2bf(float f){
  unsigned u; __builtin_memcpy(&u, &f, 4);
  u = u + 0x7FFFu + ((u >> 16) & 1u);   // round-nearest-even
  return (unsigned short)(u >> 16);
}
static __device__ __forceinline__ float sigm(float x){
  return 1.0f / (1.0f + __expf(-x));
}
static __device__ __forceinline__ float tanh_fast(float x){
  x = fminf(fmaxf(x, -15.0f), 15.0f);
  float t = __expf(2.0f * x);
  return (t - 1.0f) / (t + 1.0f);
}
static __device__ __forceinline__ int xcc_id(){
  unsigned v;
  asm volatile("s_getreg_b32 %0, hwreg(HW_REG_XCC_ID)" : "=s"(v));
  return (int)(v & 7);
}

// Per-XCD fence-free barrier (r7-proven). Data coherence: producers' stores
// reach the shared XCD L2 (vmcnt(0) drain in __syncthreads) before the flag;
// consumers first-touch via the same L2.
static __device__ __forceinline__ void xcd_barrier(int* bar, int x, int rank, int nx, int epoch){
  __syncthreads();
  int* fx = bar + OFF_FX + x * MAXRANK * FPAD;
  int* gx = bar + OFF_GX + x * FPAD;
  int nxl = min(nx, MAXRANK);
  if (rank == 0){
    for (int i = threadIdx.x + 1; i < nxl; i += 256){
      int c = 0;
      while (__hip_atomic_load(&fx[i * FPAD], __ATOMIC_RELAXED, __HIP_MEMORY_SCOPE_AGENT) < epoch && c < SPIN_CAP){
        __builtin_amdgcn_s_sleep(1); ++c;
      }
    }
    __syncthreads();
    if (threadIdx.x == 0)
      __hip_atomic_store(gx, epoch, __ATOMIC_RELAXED, __HIP_MEMORY_SCOPE_AGENT);
  } else {
    if (threadIdx.x == 0){
      __hip_atomic_store(&fx[rank * FPAD], epoch, __ATOMIC_RELAXED, __HIP_MEMORY_SCOPE_AGENT);
      int c = 0;
      while (__hip_atomic_load(gx, __ATOMIC_RELAXED, __HIP_MEMORY_SCOPE_AGENT) < epoch && c < SPIN_CAP){
        __builtin_amdgcn_s_sleep(2); ++c;
      }
    }
    __syncthreads();
  }
  asm volatile("" ::: "memory");
}

// ---------------- convert / transpose helpers ----------------

__global__ void cvt_vec4(const float4* __restrict__ x, ushort4* __restrict__ y, int n4){
  int i = blockIdx.x * 256 + threadIdx.x;
  if (i < n4){
    float4 v = x[i];
    ushort4 o;
    o.x = f2bf(v.x); o.y = f2bf(v.y); o.z = f2bf(v.z); o.w = f2bf(v.w);
    y[i] = o;
  }
}

// dstT[c*DS + koff + r] = bf16(src[r*CS + c]); tiles 32x32, block (32,8)
__global__ void transpose_cvt(const float* __restrict__ src, unsigned short* __restrict__ dstT,
                              int CS, int DS, int koff){
  __shared__ float tile[32][33];
  int c0 = blockIdx.x * 32, r0 = blockIdx.y * 32;
  int tx = threadIdx.x, ty = threadIdx.y;
  for (int i = ty; i < 32; i += 8) tile[i][tx] = src[(size_t)(r0 + i) * CS + c0 + tx];
  __syncthreads();
  for (int i = ty; i < 32; i += 8)
    dstT[(size_t)(c0 + i) * DS + koff + r0 + tx] = f2bf(tile[tx][i]);
}

// ---------------- control precompute: stack sim -> per-(XCD,level) dataflow ----------------
__global__ void precompute_ctrl(const int* __restrict__ trans,
                                int* __restrict__ srcL, int* __restrict__ srcR,
                                int* __restrict__ dstv, int* __restrict__ cnt,
                                int* __restrict__ outsrc, int* __restrict__ bar){
  __shared__ int stk[Bn][Ln + 1];    // padded
  __shared__ int scnt[NXCD * NLVL];
  __shared__ int smaxl[NXCD];
  int b = threadIdx.x;
  for (int i = b; i < NXCD * NLVL; i += 128) scnt[i] = 0;
  if (b < NXCD) smaxl[b] = 0;
  for (int i = b; i < BAR_INTS; i += 128) bar[i] = 0;
  __syncthreads();
  int x = b & 7;
  int sp = 0, bp = 0, nodecnt = 0;
  int act_next = trans[b * Tn];
  for (int t = 0; t < Tn; t++){
    int act = act_next;
    if (t + 1 < Tn) act_next = trans[b * Tn + t + 1];
    int ops = Tn - t;
    if (sp > ops) act = 2;                       // forced REDUCE (matches ref)
    if (act == 2){                               // REDUCE
      int R = stk[b][sp - 1], L = stk[b][sp - 2];
      int lvl = max(R >> 20, L >> 20) + 1;       // 1..63
      int slot = atomicAdd(&scnt[x * NLVL + lvl], 1);
      int base = (x * NLVL + lvl) * CAPX + slot;
      srcL[base] = (L & 0xFFFFF) * Hn;
      srcR[base] = (R & 0xFFFFF) * Hn;
      int noderow = LEAF_ROWS + b * (Ln - 1) + nodecnt;
      dstv[base] = noderow * Hn;
      stk[b][sp - 2] = noderow | (lvl << 20);
      sp -= 1; nodecnt++;
    } else {                                     // SHIFT (leaf: level 0)
      stk[b][sp] = b * Ln + min(bp, Ln - 1);
      sp += 1; bp += 1;
    }
  }
  int root = stk[b][max(sp - 1, 0)];
  outsrc[b] = (root & 0xFFFFF) * Hn;
  atomicMax(&smaxl[x], root >> 20);
  __syncthreads();
  for (int i = b; i < NXCD * NLVL; i += 128) cnt[i] = scnt[i];
  if (b < NXCD) cnt[NXCD * NLVL + b] = smaxl[b];
}

// ---------------- word GEMM: out = sentence @ W_word + b_word ----------------
__global__ __launch_bounds__(256) void word_gemm(
    const unsigned short* __restrict__ SB, const unsigned short* __restrict__ WwT,
    const float* __restrict__ b_word,
    unsigned short* __restrict__ HB, float* __restrict__ CF){
  int nt = blockIdx.x;            // 8 N-tiles (XCD-affine)
  int mt = blockIdx.y;            // 128 M-tiles
  int tid = threadIdx.x, w = tid >> 6, lane = tid & 63;
  int wm = w >> 1, wn = w & 1;
  int rc = lane & 15, lg = lane >> 4;
  const unsigned short* ap0 = SB + (size_t)(mt * 64 + wm * 32 + rc) * En + lg * 8;
  const unsigned short* ap1 = ap0 + (size_t)16 * En;
  const unsigned short* bp0 = WwT + (size_t)(nt * 128 + wn * 64 + rc) * En + lg * 8;
  f32x4 acc[2][4];
  #pragma unroll
  for (int h = 0; h < 2; h++)
    #pragma unroll
    for (int nb = 0; nb < 4; nb++) acc[h][nb] = (f32x4){0.f,0.f,0.f,0.f};
  #pragma unroll 4
  for (int k0 = 0; k0 < En; k0 += 32){
    bf16x8 a0 = *(const bf16x8*)(ap0 + k0);
    bf16x8 a1 = *(const bf16x8*)(ap1 + k0);
    #pragma unroll
    for (int nb = 0; nb < 4; nb++){
      bf16x8 bb = *(const bf16x8*)(bp0 + (size_t)nb * 16 * En + k0);
      acc[0][nb] = __builtin_amdgcn_mfma_f32_16x16x32_bf16(a0, bb, acc[0][nb], 0, 0, 0);
      acc[1][nb] = __builtin_amdgcn_mfma_f32_16x16x32_bf16(a1, bb, acc[1][nb], 0, 0, 0);
    }
  }
  #pragma unroll
  for (int nb = 0; nb < 4; nb++){
    int col = nt * 128 + wn * 64 + nb * 16 + rc;
    float bw = b_word[col];
    #pragma unroll
    for (int h = 0; h < 2; h++){
      #pragma unroll
      for (int q = 0; q < 4; q++){
        int row = mt * 64 + wm * 32 + h * 16 + lg * 4 + q;
        float v = acc[h][nb][q] + bw;
        if (col < Hn) HB[(size_t)row * Hn + col] = f2bf(v);
        else          CF[(size_t)row * Hn + (col - Hn)] = v;
      }
    }
  }
}

// ---------------- one 64-row x 16-u tile, full K per wave ----------------
// LDSB: gates 0-3 from LDS (swizzled), gate 4 global. Else all 5 global.
template<bool LDSB>
static __device__ __forceinline__ void tile64(
    int u02, int t, int nr, const int* __restrict__ sL, const int* __restrict__ sR,
    const int* __restrict__ dl,
    unsigned short* __restrict__ HB, float* __restrict__ CF,
    const unsigned short* __restrict__ WT, const float* __restrict__ b_red,
    const unsigned short* __restrict__ wlds, int rc, int lg)
{
  int base = t * 64;
  int offL[4], offR[4];
  #pragma unroll
  for (int m = 0; m < 4; m++){
    int i = min(base + m * 16 + rc, nr - 1);
    offL[m] = sL[i]; offR[m] = sR[i];
  }
  f32x4 acc[5][4];
  #pragma unroll
  for (int g = 0; g < 5; g++)
    #pragma unroll
    for (int m = 0; m < 4; m++) acc[g][m] = (f32x4){0.f,0.f,0.f,0.f};

  int bswz = (rc & 7) << 3;
  const unsigned short* gb0 = WT + (size_t)(0 * 512 + u02 + rc) * 1024 + lg * 8;
  const unsigned short* gb4 = WT + (size_t)(4 * 512 + u02 + rc) * 1024 + lg * 8;

  #pragma unroll 2
  for (int j = 0; j < 32; ++j){
    int k = j * 32 + lg * 8;
    bf16x8 a[4];
    #pragma unroll
    for (int m = 0; m < 4; m++){
      const unsigned short* ap = (j < 16) ? (HB + offL[m] + k) : (HB + offR[m] + (k - 512));
      a[m] = *(const bf16x8*)ap;
    }
    #pragma unroll
    for (int g = 0; g < 4; g++){
      bf16x8 bb;
      if (LDSB) bb = *(const bf16x8*)&wlds[(size_t)(g * 16 + rc) * 1024 + (k ^ bswz)];
      else      bb = *(const bf16x8*)(gb0 + (size_t)g * (512 * 1024) + j * 32);
      #pragma unroll
      for (int m = 0; m < 4; m++)
        acc[g][m] = __builtin_amdgcn_mfma_f32_16x16x32_bf16(a[m], bb, acc[g][m], 0, 0, 0);
    }
    {
      bf16x8 bb = *(const bf16x8*)(gb4 + j * 32);
      #pragma unroll
      for (int m = 0; m < 4; m++)
        acc[4][m] = __builtin_amdgcn_mfma_f32_16x16x32_bf16(a[m], bb, acc[4][m], 0, 0, 0);
    }
  }
  // lane-local LSTM epilogue: C/D row = lg*4+q, col = rc
  int colu = u02 + rc;
  float bs[5];
  #pragma unroll
  for (int g = 0; g < 5; g++) bs[g] = b_red[g * Hn + colu];
  #pragma unroll
  for (int m = 0; m < 4; m++){
    #pragma unroll
    for (int q = 0; q < 4; q++){
      int i = base + m * 16 + lg * 4 + q;
      if (i < nr){
        int oL = sL[i], oR = sR[i], oD = dl[i];
        float gv = tanh_fast(acc[0][m][q] + bs[0]);
        float iv = sigm(acc[1][m][q] + bs[1]);
        float f1 = sigm(acc[2][m][q] + bs[2]);
        float f2 = sigm(acc[3][m][q] + bs[3]);
        float ov = sigm(acc[4][m][q] + bs[4]);
        float cl = CF[oL + colu], cr = CF[oR + colu];
        float cv = gv * iv + f1 * cl + f2 * cr;
        float hv = ov * tanh_fast(cv);
        CF[oD + colu] = cv;
        HB[oD + colu] = f2bf(hv);
      }
    }
  }
}

// ---------------- persistent XCD-sharded tree kernel, LDS-resident weights ----------------
extern __shared__ unsigned short wlds[];   // 128KB dynamic

__global__ __launch_bounds__(256, 1) void tree_kernel(
    unsigned short* __restrict__ HB, float* __restrict__ CF,
    const unsigned short* __restrict__ WT, const float* __restrict__ b_red,
    const int* __restrict__ srcL, const int* __restrict__ srcR,
    const int* __restrict__ dstv, const int* __restrict__ cnt,
    const int* __restrict__ outsrc, float* __restrict__ out, int* bar){
  int bid = blockIdx.x;
  int tid = threadIdx.x, w = tid >> 6, lane = tid & 63;
  int rc = lane & 15, lg = lane >> 4;

  int x = xcc_id();
  if (tid == 0){
    int r = __hip_atomic_fetch_add(&bar[OFF_CENSUS + x * FPAD], 1,
                                   __ATOMIC_RELAXED, __HIP_MEMORY_SCOPE_AGENT);
    __hip_atomic_store(&bar[OFF_RANK + bid * FPAD], r, __ATOMIC_RELAXED, __HIP_MEMORY_SCOPE_AGENT);
  }
  __syncthreads();
  int rank = min(__hip_atomic_load(&bar[OFF_RANK + bid * FPAD], __ATOMIC_RELAXED, __HIP_MEMORY_SCOPE_AGENT),
                 MAXRANK - 1);
  int ub = rank & 31;
  int u0 = ub * 16;

  // stage gates 0..3 of this u-block into LDS (XOR-swizzled k)
  for (int gg = tid; gg < 8192; gg += 256){
    int row = gg >> 7;                 // g*16 + u
    int gk = gg & 127;
    int u = row & 15;
    int k = gk * 8;
    int g = row >> 4;
    bf16x8 v = *(const bf16x8*)(WT + (size_t)(g * 512 + u0 + u) * 1024 + k);
    int kx = k ^ ((u & 7) << 3);
    *(bf16x8*)&wlds[(size_t)row * 1024 + kx] = v;
  }
  __syncthreads();

  // global start barrier so census counts are final
  {
    int* sfl  = bar + OFF_SFLAG;
    int* sgen = bar + OFF_SGEN;
    if (bid == 0){
      for (int i = tid; i < NBLK; i += 256){
        if (i){
          int c = 0;
          while (__hip_atomic_load(&sfl[i * FPAD], __ATOMIC_RELAXED, __HIP_MEMORY_SCOPE_AGENT) == 0 && c < SPIN_CAP){
            __builtin_amdgcn_s_sleep(1); ++c;
          }
        }
      }
      __syncthreads();
      if (tid == 0) __hip_atomic_store(sgen, 1, __ATOMIC_RELAXED, __HIP_MEMORY_SCOPE_AGENT);
    } else {
      if (tid == 0){
        __hip_atomic_store(&sfl[bid * FPAD], 1, __ATOMIC_RELAXED, __HIP_MEMORY_SCOPE_AGENT);
        int c = 0;
        while (__hip_atomic_load(sgen, __ATOMIC_RELAXED, __HIP_MEMORY_SCOPE_AGENT) == 0 && c < SPIN_CAP){
          __builtin_amdgcn_s_sleep(2); ++c;
        }
      }
      __syncthreads();
    }
  }
  int nx = max(__hip_atomic_load(&bar[OFF_CENSUS + x * FPAD], __ATOMIC_RELAXED, __HIP_MEMORY_SCOPE_AGENT), 1);

  int maxlvl = cnt[NXCD * NLVL + x];
  int epoch = 1;
  for (int lvl = 1; lvl <= maxlvl; ++lvl, ++epoch){
    int nr = cnt[x * NLVL + lvl];
    const int* sL = srcL + (x * NLVL + lvl) * CAPX;
    const int* sR = srcR + (x * NLVL + lvl) * CAPX;
    const int* dl = dstv + (x * NLVL + lvl) * CAPX;
    if (nr > 0){
      int ntl = (nr + 63) >> 6;
      if (nx >= 32){
        // fixed u-block per block; tiles striped over blocks sharing this ub and waves
        int nstr = (nx - 1 - ub) / 32 + 1;
        for (int t = (rank >> 5) * 4 + w; t < ntl; t += nstr * 4)
          tile64<true>(u0, t, nr, sL, sR, dl, HB, CF, WT, b_red, wlds, rc, lg);
      } else {
        // rare fallback: cover all 32 u-blocks; LDS path only for the staged one
        int nwv = nx * 4, wid = rank * 4 + w;
        int ntask = ntl * 32;
        for (int task = wid; task < ntask; task += nwv){
          int ub2 = task / ntl, t = task - ub2 * ntl;
          if (ub2 == ub) tile64<true>(ub2 * 16, t, nr, sL, sR, dl, HB, CF, WT, b_red, wlds, rc, lg);
          else           tile64<false>(ub2 * 16, t, nr, sL, sR, dl, HB, CF, WT, b_red, wlds, rc, lg);
        }
      }
    }
    xcd_barrier(bar, x, rank, nx, epoch);
  }

  // final gather for this XCD's 16 trees
  for (int j = rank; j < 16; j += min(nx, MAXRANK)){
    int b = x + 8 * j;
    int src = outsrc[b];
    out[b * Hn + tid]       = bf2f(HB[src + tid]);
    out[b * Hn + tid + 256] = bf2f(HB[src + tid + 256]);
  }
}

// ---------------- launch ----------------
extern "C" void kernel_launch(void* const* d_in, const int* in_sizes, int n_in,
                              void* d_out, int out_size, void* d_ws, size_t ws_size,
                              hipStream_t stream){
  (void)in_sizes; (void)n_in; (void)out_size; (void)ws_size;
  const float* sentence = (const float*)d_in[0];
  const int*   trans    = (const int*)d_in[1];
  const float* W_word   = (const float*)d_in[2];
  const float* b_word   = (const float*)d_in[3];
  const float* W_left   = (const float*)d_in[4];
  const float* W_right  = (const float*)d_in[5];
  const float* b_red    = (const float*)d_in[6];

  char* ws = (char*)d_ws;
  size_t off = 0;
  auto alloc = [&](size_t bytes) -> void* {
    void* p = ws + off;
    off += (bytes + 255) & ~((size_t)255);
    return p;
  };
  unsigned short* HB  = (unsigned short*)alloc((size_t)TOT_ROWS * Hn * 2); // bf16 h
  float*          CF  = (float*)alloc((size_t)TOT_ROWS * Hn * 4);          // f32 c
  unsigned short* WT  = (unsigned short*)alloc((size_t)2560 * 1024 * 2);   // [W_left;W_right]^T bf16
  unsigned short* SB  = (unsigned short*)alloc((size_t)LEAF_ROWS * En * 2);// sentence bf16
  unsigned short* WwT = (unsigned short*)alloc((size_t)1024 * En * 2);     // W_word^T bf16
  int* srcL   = (int*)alloc((size_t)NXCD * NLVL * CAPX * 4);
  int* srcR   = (int*)alloc((size_t)NXCD * NLVL * CAPX * 4);
  int* dstv   = (int*)alloc((size_t)NXCD * NLVL * CAPX * 4);
  int* cnt    = (int*)alloc((size_t)(NXCD * NLVL + NXCD) * 4);
  int* outsrc = (int*)alloc((size_t)Bn * 4);
  int* bar    = (int*)alloc((size_t)BAR_INTS * 4);
  float* outp = (float*)d_out;

  static bool attr_set = false;
  if (!attr_set){
    hipFuncSetAttribute(reinterpret_cast<const void*>(tree_kernel),
                        hipFuncAttributeMaxDynamicSharedMemorySize, WLDS_BYTES);
    attr_set = true;
  }

  cvt_vec4<<<(LEAF_ROWS * En / 4) / 256, 256, 0, stream>>>((const float4*)sentence, (ushort4*)SB, LEAF_ROWS * En / 4);
  transpose_cvt<<<dim3(1024 / 32, En / 32), dim3(32, 8), 0, stream>>>(W_word, WwT, 1024, En, 0);
  transpose_cvt<<<dim3(2560 / 32, Hn / 32), dim3(32, 8), 0, stream>>>(W_left, WT, 2560, 1024, 0);
  transpose_cvt<<<dim3(2560 / 32, Hn / 32), dim3(32, 8), 0, stream>>>(W_right, WT, 2560, 1024, 512);
  precompute_ctrl<<<1, 128, 0, stream>>>(trans, srcL, srcR, dstv, cnt, outsrc, bar);
  word_gemm<<<dim3(8, LEAF_ROWS / 64), 256, 0, stream>>>(SB, WwT, b_word, HB, CF);
  tree_kernel<<<NBLK, 256, WLDS_BYTES, stream>>>(HB, CF, WT, b_red, srcL, srcR, dstv, cnt, outsrc, outp, bar);
}

// Round 10
// 636.565 us; speedup vs baseline: 2.8214x; 1.3308x over previous
//
#include <hip/hip_runtime.h>
#include <hip/hip_bf16.h>

// SPINN: word GEMM + XCD-sharded persistent TreeLSTM.
// Weights: gates 0-1 LDS-resident per u-block (64KB, XOR-swizzled); gates 2-4
// streamed from L2 (3MB/XCD < 4MB L2). 512 blocks = 2/CU (2 waves/SIMD),
// 2 blocks per u-block. Big levels: full-K 64-row tiles per wave with explicit
// A-prefetch. Small levels (nr<128): 16-row tiles, K split over 4 waves + LDS
// combine (chain 32->8 j-steps). Fence-free per-XCD barriers (r7-proven).
// B=128, L=64, E=512, H=512, T=127.

#define Bn 128
#define Ln 64
#define En 512
#define Hn 512
#define Tn 127
#define LEAF_ROWS (Bn*Ln)
#define NODE_ROWS (Bn*(Ln-1))
#define TOT_ROWS (LEAF_ROWS+NODE_ROWS)
#define NLVL 64
#define NXCD 8
#define CAPX 512                 // max rows per XCD-bin per level
#define NBLK 512                 // 2 blocks/CU
#define FPAD 16
#define MAXRANK 96
#define SPIN_CAP (1<<22)
#define WLDS_BYTES 65536         // 2 gates x 16u x 1024k x 2B
#define PART_BYTES (4*2*16*20*4) // [wave][gatepair][row][col+pad] f32
#define DYN_BYTES (WLDS_BYTES + PART_BYTES)

// barrier/census state layout (ints), zeroed by precompute_ctrl each call
#define OFF_CENSUS 0                              // NXCD*FPAD
#define OFF_RANK   (OFF_CENSUS + NXCD*FPAD)       // NBLK*FPAD
#define OFF_SFLAG  (OFF_RANK + NBLK*FPAD)         // NBLK*FPAD
#define OFF_SGEN   (OFF_SFLAG + NBLK*FPAD)        // FPAD
#define OFF_FX     (OFF_SGEN + FPAD)              // NXCD*MAXRANK*FPAD
#define OFF_GX     (OFF_FX + NXCD*MAXRANK*FPAD)   // NXCD*FPAD
#define BAR_INTS   (OFF_GX + NXCD*FPAD)

typedef __attribute__((ext_vector_type(8))) short bf16x8;
typedef __attribute__((ext_vector_type(4))) float f32x4;

static __device__ __forceinline__ float bf2f(unsigned short u){
  unsigned v = ((unsigned)u) << 16;
  float f; __builtin_memcpy(&f, &v, 4); return f;
}
static __device__ __forceinline__ unsigned short f2bf(float f){
  unsigned u; __builtin_memcpy(&u, &f, 4);
  u = u + 0x7FFFu + ((u >> 16) & 1u);   // round-nearest-even
  return (unsigned short)(u >> 16);
}
static __device__ __forceinline__ float sigm(float x){
  return 1.0f / (1.0f + __expf(-x));
}
static __device__ __forceinline__ float tanh_fast(float x){
  x = fminf(fmaxf(x, -15.0f), 15.0f);
  float t = __expf(2.0f * x);
  return (t - 1.0f) / (t + 1.0f);
}
static __device__ __forceinline__ int xcc_id(){
  unsigned v;
  asm volatile("s_getreg_b32 %0, hwreg(HW_REG_XCC_ID)" : "=s"(v));
  return (int)(v & 7);
}

// Per-XCD fence-free barrier (r7-proven).
static __device__ __forceinline__ void xcd_barrier(int* bar, int x, int rank, int nx, int epoch){
  __syncthreads();
  int* fx = bar + OFF_FX + x * MAXRANK * FPAD;
  int* gx = bar + OFF_GX + x * FPAD;
  int nxl = min(nx, MAXRANK);
  if (rank == 0){
    for (int i = threadIdx.x + 1; i < nxl; i += 256){
      int c = 0;
      while (__hip_atomic_load(&fx[i * FPAD], __ATOMIC_RELAXED, __HIP_MEMORY_SCOPE_AGENT) < epoch && c < SPIN_CAP){
        __builtin_amdgcn_s_sleep(1); ++c;
      }
    }
    __syncthreads();
    if (threadIdx.x == 0)
      __hip_atomic_store(gx, epoch, __ATOMIC_RELAXED, __HIP_MEMORY_SCOPE_AGENT);
  } else {
    if (threadIdx.x == 0){
      __hip_atomic_store(&fx[rank * FPAD], epoch, __ATOMIC_RELAXED, __HIP_MEMORY_SCOPE_AGENT);
      int c = 0;
      while (__hip_atomic_load(gx, __ATOMIC_RELAXED, __HIP_MEMORY_SCOPE_AGENT) < epoch && c < SPIN_CAP){
        __builtin_amdgcn_s_sleep(2); ++c;
      }
    }
    __syncthreads();
  }
  asm volatile("" ::: "memory");
}

// ---------------- convert / transpose helpers ----------------

__global__ void cvt_vec4(const float4* __restrict__ x, ushort4* __restrict__ y, int n4){
  int i = blockIdx.x * 256 + threadIdx.x;
  if (i < n4){
    float4 v = x[i];
    ushort4 o;
    o.x = f2bf(v.x); o.y = f2bf(v.y); o.z = f2bf(v.z); o.w = f2bf(v.w);
    y[i] = o;
  }
}

__global__ void transpose_cvt(const float* __restrict__ src, unsigned short* __restrict__ dstT,
                              int CS, int DS, int koff){
  __shared__ float tile[32][33];
  int c0 = blockIdx.x * 32, r0 = blockIdx.y * 32;
  int tx = threadIdx.x, ty = threadIdx.y;
  for (int i = ty; i < 32; i += 8) tile[i][tx] = src[(size_t)(r0 + i) * CS + c0 + tx];
  __syncthreads();
  for (int i = ty; i < 32; i += 8)
    dstT[(size_t)(c0 + i) * DS + koff + r0 + tx] = f2bf(tile[tx][i]);
}

// ---------------- control precompute ----------------
__global__ void precompute_ctrl(const int* __restrict__ trans,
                                int* __restrict__ srcL, int* __restrict__ srcR,
                                int* __restrict__ dstv, int* __restrict__ cnt,
                                int* __restrict__ outsrc, int* __restrict__ bar){
  __shared__ int stk[Bn][Ln + 1];
  __shared__ int scnt[NXCD * NLVL];
  __shared__ int smaxl[NXCD];
  int b = threadIdx.x;
  for (int i = b; i < NXCD * NLVL; i += 128) scnt[i] = 0;
  if (b < NXCD) smaxl[b] = 0;
  for (int i = b; i < BAR_INTS; i += 128) bar[i] = 0;
  __syncthreads();
  int x = b & 7;
  int sp = 0, bp = 0, nodecnt = 0;
  int act_next = trans[b * Tn];
  for (int t = 0; t < Tn; t++){
    int act = act_next;
    if (t + 1 < Tn) act_next = trans[b * Tn + t + 1];
    int ops = Tn - t;
    if (sp > ops) act = 2;                       // forced REDUCE (matches ref)
    if (act == 2){
      int R = stk[b][sp - 1], L = stk[b][sp - 2];
      int lvl = max(R >> 20, L >> 20) + 1;
      int slot = atomicAdd(&scnt[x * NLVL + lvl], 1);
      int base = (x * NLVL + lvl) * CAPX + slot;
      srcL[base] = (L & 0xFFFFF) * Hn;
      srcR[base] = (R & 0xFFFFF) * Hn;
      int noderow = LEAF_ROWS + b * (Ln - 1) + nodecnt;
      dstv[base] = noderow * Hn;
      stk[b][sp - 2] = noderow | (lvl << 20);
      sp -= 1; nodecnt++;
    } else {
      stk[b][sp] = b * Ln + min(bp, Ln - 1);
      sp += 1; bp += 1;
    }
  }
  int root = stk[b][max(sp - 1, 0)];
  outsrc[b] = (root & 0xFFFFF) * Hn;
  atomicMax(&smaxl[x], root >> 20);
  __syncthreads();
  for (int i = b; i < NXCD * NLVL; i += 128) cnt[i] = scnt[i];
  if (b < NXCD) cnt[NXCD * NLVL + b] = smaxl[b];
}

// ---------------- word GEMM ----------------
__global__ __launch_bounds__(256) void word_gemm(
    const unsigned short* __restrict__ SB, const unsigned short* __restrict__ WwT,
    const float* __restrict__ b_word,
    unsigned short* __restrict__ HB, float* __restrict__ CF){
  int nt = blockIdx.x;
  int mt = blockIdx.y;
  int tid = threadIdx.x, w = tid >> 6, lane = tid & 63;
  int wm = w >> 1, wn = w & 1;
  int rc = lane & 15, lg = lane >> 4;
  const unsigned short* ap0 = SB + (size_t)(mt * 64 + wm * 32 + rc) * En + lg * 8;
  const unsigned short* ap1 = ap0 + (size_t)16 * En;
  const unsigned short* bp0 = WwT + (size_t)(nt * 128 + wn * 64 + rc) * En + lg * 8;
  f32x4 acc[2][4];
  #pragma unroll
  for (int h = 0; h < 2; h++)
    #pragma unroll
    for (int nb = 0; nb < 4; nb++) acc[h][nb] = (f32x4){0.f,0.f,0.f,0.f};
  #pragma unroll 4
  for (int k0 = 0; k0 < En; k0 += 32){
    bf16x8 a0 = *(const bf16x8*)(ap0 + k0);
    bf16x8 a1 = *(const bf16x8*)(ap1 + k0);
    #pragma unroll
    for (int nb = 0; nb < 4; nb++){
      bf16x8 bb = *(const bf16x8*)(bp0 + (size_t)nb * 16 * En + k0);
      acc[0][nb] = __builtin_amdgcn_mfma_f32_16x16x32_bf16(a0, bb, acc[0][nb], 0, 0, 0);
      acc[1][nb] = __builtin_amdgcn_mfma_f32_16x16x32_bf16(a1, bb, acc[1][nb], 0, 0, 0);
    }
  }
  #pragma unroll
  for (int nb = 0; nb < 4; nb++){
    int col = nt * 128 + wn * 64 + nb * 16 + rc;
    float bw = b_word[col];
    #pragma unroll
    for (int h = 0; h < 2; h++){
      #pragma unroll
      for (int q = 0; q < 4; q++){
        int row = mt * 64 + wm * 32 + h * 16 + lg * 4 + q;
        float v = acc[h][nb][q] + bw;
        if (col < Hn) HB[(size_t)row * Hn + col] = f2bf(v);
        else          CF[(size_t)row * Hn + (col - Hn)] = v;
      }
    }
  }
}

// ---------------- big-level tile: 64 rows x 16 u, full K per wave ----------------
// LDSB: gates 0-1 from LDS (swizzled); gates 2-4 (or all 5 if !LDSB) global.
// Explicit A-prefetch: j+1's fragments load during j's MFMAs.
template<bool LDSB>
static __device__ __forceinline__ void tile64(
    int u0, int t, int nr, const int* __restrict__ sL, const int* __restrict__ sR,
    const int* __restrict__ dl,
    unsigned short* __restrict__ HB, float* __restrict__ CF,
    const unsigned short* __restrict__ WT, const float* __restrict__ b_red,
    const unsigned short* __restrict__ wlds, int rc, int lg)
{
  int base = t * 64;
  int offL[4], offR[4];
  #pragma unroll
  for (int m = 0; m < 4; m++){
    int i = min(base + m * 16 + rc, nr - 1);
    offL[m] = sL[i]; offR[m] = sR[i];
  }
  f32x4 acc[5][4];
  #pragma unroll
  for (int g = 0; g < 5; g++)
    #pragma unroll
    for (int m = 0; m < 4; m++) acc[g][m] = (f32x4){0.f,0.f,0.f,0.f};

  int bswz = (rc & 7) << 3;
  const unsigned short* gb = WT + (size_t)(u0 + rc) * 1024 + lg * 8;

  bf16x8 a_cur[4];
  #pragma unroll
  for (int m = 0; m < 4; m++) a_cur[m] = *(const bf16x8*)(HB + offL[m] + lg * 8);

  #pragma unroll 4
  for (int j = 0; j < 32; ++j){
    bf16x8 a_nxt[4];
    if (j < 31){
      int kn = (j + 1) * 32 + lg * 8;
      #pragma unroll
      for (int m = 0; m < 4; m++){
        const unsigned short* ap = (j + 1 < 16) ? (HB + offL[m] + kn) : (HB + offR[m] + (kn - 512));
        a_nxt[m] = *(const bf16x8*)ap;
      }
    }
    int k = j * 32 + lg * 8;
    #pragma unroll
    for (int g = 0; g < 5; g++){
      bf16x8 bb;
      if (LDSB && g < 2) bb = *(const bf16x8*)&wlds[(size_t)(g * 16 + rc) * 1024 + (k ^ bswz)];
      else               bb = *(const bf16x8*)(gb + (size_t)g * (512 * 1024) + j * 32);
      #pragma unroll
      for (int m = 0; m < 4; m++)
        acc[g][m] = __builtin_amdgcn_mfma_f32_16x16x32_bf16(a_cur[m], bb, acc[g][m], 0, 0, 0);
    }
    #pragma unroll
    for (int m = 0; m < 4; m++) a_cur[m] = a_nxt[m];
  }
  // lane-local LSTM epilogue: C/D row = lg*4+q, col = rc
  int colu = u0 + rc;
  float bs[5];
  #pragma unroll
  for (int g = 0; g < 5; g++) bs[g] = b_red[g * Hn + colu];
  #pragma unroll
  for (int m = 0; m < 4; m++){
    #pragma unroll
    for (int q = 0; q < 4; q++){
      int i = base + m * 16 + lg * 4 + q;
      if (i < nr){
        int oL = sL[i], oR = sR[i], oD = dl[i];
        float gv = tanh_fast(acc[0][m][q] + bs[0]);
        float iv = sigm(acc[1][m][q] + bs[1]);
        float f1 = sigm(acc[2][m][q] + bs[2]);
        float f2 = sigm(acc[3][m][q] + bs[3]);
        float ov = sigm(acc[4][m][q] + bs[4]);
        float cl = CF[oL + colu], cr = CF[oR + colu];
        float cv = gv * iv + f1 * cl + f2 * cr;
        float hv = ov * tanh_fast(cv);
        CF[oD + colu] = cv;
        HB[oD + colu] = f2bf(hv);
      }
    }
  }
}

// ---------------- small-level tile: 16 rows x 16 u, K split over 4 waves ----------------
static __device__ __forceinline__ void tile16(
    int u0, int t, int nr, const int* __restrict__ sL, const int* __restrict__ sR,
    const int* __restrict__ dl,
    unsigned short* __restrict__ HB, float* __restrict__ CF,
    const unsigned short* __restrict__ WT, const float* __restrict__ b_red,
    const unsigned short* __restrict__ wlds, float (*part)[2][16][20],
    int tid, int w, int rc, int lg)
{
  int base = t * 16;
  int i0 = min(base + rc, nr - 1);
  int offA = (w >= 2) ? sR[i0] : sL[i0];
  int k0 = w * 256;                       // this wave's K quarter (of 1024)
  int abase = (w >= 2) ? (k0 - 512) : k0; // child-local K offset
  const unsigned short* ap = HB + offA + abase + lg * 8;
  int bswz = (rc & 7) << 3;
  const unsigned short* gb = WT + (size_t)(u0 + rc) * 1024;

  f32x4 acc[5];
  #pragma unroll
  for (int g = 0; g < 5; g++) acc[g] = (f32x4){0.f,0.f,0.f,0.f};
  #pragma unroll
  for (int j = 0; j < 8; ++j){
    int k = k0 + j * 32 + lg * 8;
    bf16x8 a = *(const bf16x8*)(ap + j * 32);
    #pragma unroll
    for (int g = 0; g < 5; g++){
      bf16x8 bb;
      if (g < 2) bb = *(const bf16x8*)&wlds[(size_t)(g * 16 + rc) * 1024 + (k ^ bswz)];
      else       bb = *(const bf16x8*)(gb + (size_t)g * (512 * 1024) + k);
      acc[g] = __builtin_amdgcn_mfma_f32_16x16x32_bf16(a, bb, acc[g], 0, 0, 0);
    }
  }
  // combine across waves, gate pairs (LDS [4][2][16][20])
  int er = tid >> 4, eu = tid & 15;
  float sg[5];
  #pragma unroll
  for (int r = 0; r < 3; ++r){
    int ng = (r < 2) ? 2 : 1;
    #pragma unroll
    for (int gi = 0; gi < 2; ++gi){
      if (gi < ng){
        int g = r * 2 + gi;
        #pragma unroll
        for (int q = 0; q < 4; q++) part[w][gi][lg * 4 + q][rc] = acc[g][q];
      }
    }
    __syncthreads();
    #pragma unroll
    for (int gi = 0; gi < 2; ++gi){
      if (gi < ng)
        sg[r * 2 + gi] = part[0][gi][er][eu] + part[1][gi][er][eu]
                       + part[2][gi][er][eu] + part[3][gi][er][eu];
    }
    __syncthreads();
  }
  int i = base + er;
  if (i < nr){
    int colu = u0 + eu;
    int oL = sL[i], oR = sR[i], oD = dl[i];
    float gv = tanh_fast(sg[0] + b_red[colu]);
    float iv = sigm(sg[1] + b_red[Hn + colu]);
    float f1 = sigm(sg[2] + b_red[2 * Hn + colu]);
    float f2 = sigm(sg[3] + b_red[3 * Hn + colu]);
    float ov = sigm(sg[4] + b_red[4 * Hn + colu]);
    float cl = CF[oL + colu], cr = CF[oR + colu];
    float cv = gv * iv + f1 * cl + f2 * cr;
    float hv = ov * tanh_fast(cv);
    CF[oD + colu] = cv;
    HB[oD + colu] = f2bf(hv);
  }
  __syncthreads();
}

// ---------------- persistent XCD-sharded tree kernel ----------------
extern __shared__ char dynbuf[];

__global__ __launch_bounds__(256, 2) void tree_kernel(
    unsigned short* __restrict__ HB, float* __restrict__ CF,
    const unsigned short* __restrict__ WT, const float* __restrict__ b_red,
    const int* __restrict__ srcL, const int* __restrict__ srcR,
    const int* __restrict__ dstv, const int* __restrict__ cnt,
    const int* __restrict__ outsrc, float* __restrict__ out, int* bar){
  unsigned short* wlds = (unsigned short*)dynbuf;             // 64KB: gates 0-1
  float (*part)[2][16][20] = (float(*)[2][16][20])(dynbuf + WLDS_BYTES);
  int bid = blockIdx.x;
  int tid = threadIdx.x, w = tid >> 6, lane = tid & 63;
  int rc = lane & 15, lg = lane >> 4;

  int x = xcc_id();
  if (tid == 0){
    int r = __hip_atomic_fetch_add(&bar[OFF_CENSUS + x * FPAD], 1,
                                   __ATOMIC_RELAXED, __HIP_MEMORY_SCOPE_AGENT);
    __hip_atomic_store(&bar[OFF_RANK + bid * FPAD], r, __ATOMIC_RELAXED, __HIP_MEMORY_SCOPE_AGENT);
  }
  __syncthreads();
  int rank = min(__hip_atomic_load(&bar[OFF_RANK + bid * FPAD], __ATOMIC_RELAXED, __HIP_MEMORY_SCOPE_AGENT),
                 MAXRANK - 1);
  int ub = rank & 31;
  int u0 = ub * 16;

  // stage gates 0-1 of this u-block into LDS (XOR-swizzled k)
  for (int gg = tid; gg < 4096; gg += 256){
    int row = gg >> 7;                 // g*16 + u, 0..31
    int k = (gg & 127) * 8;
    int u = row & 15, g = row >> 4;
    bf16x8 v = *(const bf16x8*)(WT + (size_t)(g * 512 + u0 + u) * 1024 + k);
    int kx = k ^ ((u & 7) << 3);
    *(bf16x8*)&wlds[(size_t)row * 1024 + kx] = v;
  }
  __syncthreads();

  // global start barrier so census counts are final
  {
    int* sfl  = bar + OFF_SFLAG;
    int* sgen = bar + OFF_SGEN;
    if (bid == 0){
      for (int i = tid; i < NBLK; i += 256){
        if (i){
          int c = 0;
          while (__hip_atomic_load(&sfl[i * FPAD], __ATOMIC_RELAXED, __HIP_MEMORY_SCOPE_AGENT) == 0 && c < SPIN_CAP){
            __builtin_amdgcn_s_sleep(1); ++c;
          }
        }
      }
      __syncthreads();
      if (tid == 0) __hip_atomic_store(sgen, 1, __ATOMIC_RELAXED, __HIP_MEMORY_SCOPE_AGENT);
    } else {
      if (tid == 0){
        __hip_atomic_store(&sfl[bid * FPAD], 1, __ATOMIC_RELAXED, __HIP_MEMORY_SCOPE_AGENT);
        int c = 0;
        while (__hip_atomic_load(sgen, __ATOMIC_RELAXED, __HIP_MEMORY_SCOPE_AGENT) == 0 && c < SPIN_CAP){
          __builtin_amdgcn_s_sleep(2); ++c;
        }
      }
      __syncthreads();
    }
  }
  int nx = max(__hip_atomic_load(&bar[OFF_CENSUS + x * FPAD], __ATOMIC_RELAXED, __HIP_MEMORY_SCOPE_AGENT), 1);

  int maxlvl = cnt[NXCD * NLVL + x];
  int epoch = 1;
  for (int lvl = 1; lvl <= maxlvl; ++lvl, ++epoch){
    int nr = cnt[x * NLVL + lvl];
    const int* sL = srcL + (x * NLVL + lvl) * CAPX;
    const int* sR = srcR + (x * NLVL + lvl) * CAPX;
    const int* dl = dstv + (x * NLVL + lvl) * CAPX;
    if (nr > 0){
      if (nx >= 32){
        int nstr = (nx - 1 - ub) / 32 + 1;     // blocks sharing this ub
        int stripe = rank >> 5;
        if (nr >= 128){
          int ntl = (nr + 63) >> 6;
          for (int t = stripe * 4 + w; t < ntl; t += nstr * 4)
            tile64<true>(u0, t, nr, sL, sR, dl, HB, CF, WT, b_red, wlds, rc, lg);
        } else {
          int ntl16 = (nr + 15) >> 4;
          for (int t = stripe; t < ntl16; t += nstr)
            tile16(u0, t, nr, sL, sR, dl, HB, CF, WT, b_red, wlds, part, tid, w, rc, lg);
        }
      } else {
        // rare fallback: cover all 32 u-blocks from global
        int ntl = (nr + 63) >> 6;
        int nwv = nx * 4, wid = rank * 4 + w;
        int ntask = ntl * 32;
        for (int task = wid; task < ntask; task += nwv)
          tile64<false>((task / ntl) * 16, task % ntl, nr, sL, sR, dl, HB, CF, WT, b_red, wlds, rc, lg);
      }
    }
    xcd_barrier(bar, x, rank, nx, epoch);
  }

  // final gather for this XCD's 16 trees
  for (int j = rank; j < 16; j += min(nx, MAXRANK)){
    int b = x + 8 * j;
    int src = outsrc[b];
    out[b * Hn + tid]       = bf2f(HB[src + tid]);
    out[b * Hn + tid + 256] = bf2f(HB[src + tid + 256]);
  }
}

// ---------------- launch ----------------
extern "C" void kernel_launch(void* const* d_in, const int* in_sizes, int n_in,
                              void* d_out, int out_size, void* d_ws, size_t ws_size,
                              hipStream_t stream){
  (void)in_sizes; (void)n_in; (void)out_size; (void)ws_size;
  const float* sentence = (const float*)d_in[0];
  const int*   trans    = (const int*)d_in[1];
  const float* W_word   = (const float*)d_in[2];
  const float* b_word   = (const float*)d_in[3];
  const float* W_left   = (const float*)d_in[4];
  const float* W_right  = (const float*)d_in[5];
  const float* b_red    = (const float*)d_in[6];

  char* ws = (char*)d_ws;
  size_t off = 0;
  auto alloc = [&](size_t bytes) -> void* {
    void* p = ws + off;
    off += (bytes + 255) & ~((size_t)255);
    return p;
  };
  unsigned short* HB  = (unsigned short*)alloc((size_t)TOT_ROWS * Hn * 2);
  float*          CF  = (float*)alloc((size_t)TOT_ROWS * Hn * 4);
  unsigned short* WT  = (unsigned short*)alloc((size_t)2560 * 1024 * 2);
  unsigned short* SB  = (unsigned short*)alloc((size_t)LEAF_ROWS * En * 2);
  unsigned short* WwT = (unsigned short*)alloc((size_t)1024 * En * 2);
  int* srcL   = (int*)alloc((size_t)NXCD * NLVL * CAPX * 4);
  int* srcR   = (int*)alloc((size_t)NXCD * NLVL * CAPX * 4);
  int* dstv   = (int*)alloc((size_t)NXCD * NLVL * CAPX * 4);
  int* cnt    = (int*)alloc((size_t)(NXCD * NLVL + NXCD) * 4);
  int* outsrc = (int*)alloc((size_t)Bn * 4);
  int* bar    = (int*)alloc((size_t)BAR_INTS * 4);
  float* outp = (float*)d_out;

  hipFuncSetAttribute(reinterpret_cast<const void*>(tree_kernel),
                      hipFuncAttributeMaxDynamicSharedMemorySize, DYN_BYTES);

  cvt_vec4<<<(LEAF_ROWS * En / 4) / 256, 256, 0, stream>>>((const float4*)sentence, (ushort4*)SB, LEAF_ROWS * En / 4);
  transpose_cvt<<<dim3(1024 / 32, En / 32), dim3(32, 8), 0, stream>>>(W_word, WwT, 1024, En, 0);
  transpose_cvt<<<dim3(2560 / 32, Hn / 32), dim3(32, 8), 0, stream>>>(W_left, WT, 2560, 1024, 0);
  transpose_cvt<<<dim3(2560 / 32, Hn / 32), dim3(32, 8), 0, stream>>>(W_right, WT, 2560, 1024, 512);
  precompute_ctrl<<<1, 128, 0, stream>>>(trans, srcL, srcR, dstv, cnt, outsrc, bar);
  word_gemm<<<dim3(8, LEAF_ROWS / 64), 256, 0, stream>>>(SB, WwT, b_word, HB, CF);
  tree_kernel<<<NBLK, 256, DYN_BYTES, stream>>>(HB, CF, WT, b_red, srcL, srcR, dstv, cnt, outsrc, outp, bar);
}

// Round 11
// 599.191 us; speedup vs baseline: 2.9974x; 1.0624x over previous
//
#include <hip/hip_runtime.h>
#include <hip/hip_bf16.h>

// SPINN: word GEMM + XCD-sharded persistent TreeLSTM.
// r11: r10 + non-temporal CF traffic (C rows are read-once -> bypass L2 so the
// 3MB/XCD streamed gate set stays L2-resident) + B-prefetch for gates 2-4.
// Weights: gates 0-1 LDS-resident per u-block (64KB, XOR-swizzled); gates 2-4
// streamed from L2. 512 blocks = 2/CU, 2 blocks per u-block. Fence-free
// per-XCD barriers (r7-proven).
// B=128, L=64, E=512, H=512, T=127.

#define Bn 128
#define Ln 64
#define En 512
#define Hn 512
#define Tn 127
#define LEAF_ROWS (Bn*Ln)
#define NODE_ROWS (Bn*(Ln-1))
#define TOT_ROWS (LEAF_ROWS+NODE_ROWS)
#define NLVL 64
#define NXCD 8
#define CAPX 512                 // max rows per XCD-bin per level
#define NBLK 512                 // 2 blocks/CU
#define FPAD 16
#define MAXRANK 96
#define SPIN_CAP (1<<22)
#define WLDS_BYTES 65536         // 2 gates x 16u x 1024k x 2B
#define PART_BYTES (4*2*16*20*4) // [wave][gatepair][row][col+pad] f32
#define DYN_BYTES (WLDS_BYTES + PART_BYTES)

// barrier/census state layout (ints), zeroed by precompute_ctrl each call
#define OFF_CENSUS 0                              // NXCD*FPAD
#define OFF_RANK   (OFF_CENSUS + NXCD*FPAD)       // NBLK*FPAD
#define OFF_SFLAG  (OFF_RANK + NBLK*FPAD)         // NBLK*FPAD
#define OFF_SGEN   (OFF_SFLAG + NBLK*FPAD)        // FPAD
#define OFF_FX     (OFF_SGEN + FPAD)              // NXCD*MAXRANK*FPAD
#define OFF_GX     (OFF_FX + NXCD*MAXRANK*FPAD)   // NXCD*FPAD
#define BAR_INTS   (OFF_GX + NXCD*FPAD)

typedef __attribute__((ext_vector_type(8))) short bf16x8;
typedef __attribute__((ext_vector_type(4))) float f32x4;

static __device__ __forceinline__ float bf2f(unsigned short u){
  unsigned v = ((unsigned)u) << 16;
  float f; __builtin_memcpy(&f, &v, 4); return f;
}
static __device__ __forceinline__ unsigned short f2bf(float f){
  unsigned u; __builtin_memcpy(&u, &f, 4);
  u = u + 0x7FFFu + ((u >> 16) & 1u);   // round-nearest-even
  return (unsigned short)(u >> 16);
}
static __device__ __forceinline__ float sigm(float x){
  return 1.0f / (1.0f + __expf(-x));
}
static __device__ __forceinline__ float tanh_fast(float x){
  x = fminf(fmaxf(x, -15.0f), 15.0f);
  float t = __expf(2.0f * x);
  return (t - 1.0f) / (t + 1.0f);
}
static __device__ __forceinline__ int xcc_id(){
  unsigned v;
  asm volatile("s_getreg_b32 %0, hwreg(HW_REG_XCC_ID)" : "=s"(v));
  return (int)(v & 7);
}

// Per-XCD fence-free barrier (r7-proven).
static __device__ __forceinline__ void xcd_barrier(int* bar, int x, int rank, int nx, int epoch){
  __syncthreads();
  int* fx = bar + OFF_FX + x * MAXRANK * FPAD;
  int* gx = bar + OFF_GX + x * FPAD;
  int nxl = min(nx, MAXRANK);
  if (rank == 0){
    for (int i = threadIdx.x + 1; i < nxl; i += 256){
      int c = 0;
      while (__hip_atomic_load(&fx[i * FPAD], __ATOMIC_RELAXED, __HIP_MEMORY_SCOPE_AGENT) < epoch && c < SPIN_CAP){
        __builtin_amdgcn_s_sleep(1); ++c;
      }
    }
    __syncthreads();
    if (threadIdx.x == 0)
      __hip_atomic_store(gx, epoch, __ATOMIC_RELAXED, __HIP_MEMORY_SCOPE_AGENT);
  } else {
    if (threadIdx.x == 0){
      __hip_atomic_store(&fx[rank * FPAD], epoch, __ATOMIC_RELAXED, __HIP_MEMORY_SCOPE_AGENT);
      int c = 0;
      while (__hip_atomic_load(gx, __ATOMIC_RELAXED, __HIP_MEMORY_SCOPE_AGENT) < epoch && c < SPIN_CAP){
        __builtin_amdgcn_s_sleep(2); ++c;
      }
    }
    __syncthreads();
  }
  asm volatile("" ::: "memory");
}

// ---------------- convert / transpose helpers ----------------

__global__ void cvt_vec4(const float4* __restrict__ x, ushort4* __restrict__ y, int n4){
  int i = blockIdx.x * 256 + threadIdx.x;
  if (i < n4){
    float4 v = x[i];
    ushort4 o;
    o.x = f2bf(v.x); o.y = f2bf(v.y); o.z = f2bf(v.z); o.w = f2bf(v.w);
    y[i] = o;
  }
}

__global__ void transpose_cvt(const float* __restrict__ src, unsigned short* __restrict__ dstT,
                              int CS, int DS, int koff){
  __shared__ float tile[32][33];
  int c0 = blockIdx.x * 32, r0 = blockIdx.y * 32;
  int tx = threadIdx.x, ty = threadIdx.y;
  for (int i = ty; i < 32; i += 8) tile[i][tx] = src[(size_t)(r0 + i) * CS + c0 + tx];
  __syncthreads();
  for (int i = ty; i < 32; i += 8)
    dstT[(size_t)(c0 + i) * DS + koff + r0 + tx] = f2bf(tile[tx][i]);
}

// ---------------- control precompute ----------------
__global__ void precompute_ctrl(const int* __restrict__ trans,
                                int* __restrict__ srcL, int* __restrict__ srcR,
                                int* __restrict__ dstv, int* __restrict__ cnt,
                                int* __restrict__ outsrc, int* __restrict__ bar){
  __shared__ int stk[Bn][Ln + 1];
  __shared__ int scnt[NXCD * NLVL];
  __shared__ int smaxl[NXCD];
  int b = threadIdx.x;
  for (int i = b; i < NXCD * NLVL; i += 128) scnt[i] = 0;
  if (b < NXCD) smaxl[b] = 0;
  for (int i = b; i < BAR_INTS; i += 128) bar[i] = 0;
  __syncthreads();
  int x = b & 7;
  int sp = 0, bp = 0, nodecnt = 0;
  int act_next = trans[b * Tn];
  for (int t = 0; t < Tn; t++){
    int act = act_next;
    if (t + 1 < Tn) act_next = trans[b * Tn + t + 1];
    int ops = Tn - t;
    if (sp > ops) act = 2;                       // forced REDUCE (matches ref)
    if (act == 2){
      int R = stk[b][sp - 1], L = stk[b][sp - 2];
      int lvl = max(R >> 20, L >> 20) + 1;
      int slot = atomicAdd(&scnt[x * NLVL + lvl], 1);
      int base = (x * NLVL + lvl) * CAPX + slot;
      srcL[base] = (L & 0xFFFFF) * Hn;
      srcR[base] = (R & 0xFFFFF) * Hn;
      int noderow = LEAF_ROWS + b * (Ln - 1) + nodecnt;
      dstv[base] = noderow * Hn;
      stk[b][sp - 2] = noderow | (lvl << 20);
      sp -= 1; nodecnt++;
    } else {
      stk[b][sp] = b * Ln + min(bp, Ln - 1);
      sp += 1; bp += 1;
    }
  }
  int root = stk[b][max(sp - 1, 0)];
  outsrc[b] = (root & 0xFFFFF) * Hn;
  atomicMax(&smaxl[x], root >> 20);
  __syncthreads();
  for (int i = b; i < NXCD * NLVL; i += 128) cnt[i] = scnt[i];
  if (b < NXCD) cnt[NXCD * NLVL + b] = smaxl[b];
}

// ---------------- word GEMM ----------------
__global__ __launch_bounds__(256) void word_gemm(
    const unsigned short* __restrict__ SB, const unsigned short* __restrict__ WwT,
    const float* __restrict__ b_word,
    unsigned short* __restrict__ HB, float* __restrict__ CF){
  int nt = blockIdx.x;
  int mt = blockIdx.y;
  int tid = threadIdx.x, w = tid >> 6, lane = tid & 63;
  int wm = w >> 1, wn = w & 1;
  int rc = lane & 15, lg = lane >> 4;
  const unsigned short* ap0 = SB + (size_t)(mt * 64 + wm * 32 + rc) * En + lg * 8;
  const unsigned short* ap1 = ap0 + (size_t)16 * En;
  const unsigned short* bp0 = WwT + (size_t)(nt * 128 + wn * 64 + rc) * En + lg * 8;
  f32x4 acc[2][4];
  #pragma unroll
  for (int h = 0; h < 2; h++)
    #pragma unroll
    for (int nb = 0; nb < 4; nb++) acc[h][nb] = (f32x4){0.f,0.f,0.f,0.f};
  #pragma unroll 4
  for (int k0 = 0; k0 < En; k0 += 32){
    bf16x8 a0 = *(const bf16x8*)(ap0 + k0);
    bf16x8 a1 = *(const bf16x8*)(ap1 + k0);
    #pragma unroll
    for (int nb = 0; nb < 4; nb++){
      bf16x8 bb = *(const bf16x8*)(bp0 + (size_t)nb * 16 * En + k0);
      acc[0][nb] = __builtin_amdgcn_mfma_f32_16x16x32_bf16(a0, bb, acc[0][nb], 0, 0, 0);
      acc[1][nb] = __builtin_amdgcn_mfma_f32_16x16x32_bf16(a1, bb, acc[1][nb], 0, 0, 0);
    }
  }
  #pragma unroll
  for (int nb = 0; nb < 4; nb++){
    int col = nt * 128 + wn * 64 + nb * 16 + rc;
    float bw = b_word[col];
    #pragma unroll
    for (int h = 0; h < 2; h++){
      #pragma unroll
      for (int q = 0; q < 4; q++){
        int row = mt * 64 + wm * 32 + h * 16 + lg * 4 + q;
        float v = acc[h][nb][q] + bw;
        if (col < Hn) HB[(size_t)row * Hn + col] = f2bf(v);
        else          CF[(size_t)row * Hn + (col - Hn)] = v;
      }
    }
  }
}

// ---------------- big-level tile: 64 rows x 16 u, full K per wave ----------------
// Gates 0-1 from LDS (swizzled); gates 2-4 global with 1-step register prefetch
// (as is A). CF accesses non-temporal (read-once data; keep weights in L2).
template<bool LDSB>
static __device__ __forceinline__ void tile64(
    int u0, int t, int nr, const int* __restrict__ sL, const int* __restrict__ sR,
    const int* __restrict__ dl,
    unsigned short* __restrict__ HB, float* __restrict__ CF,
    const unsigned short* __restrict__ WT, const float* __restrict__ b_red,
    const unsigned short* __restrict__ wlds, int rc, int lg)
{
  int base = t * 64;
  int offL[4], offR[4];
  #pragma unroll
  for (int m = 0; m < 4; m++){
    int i = min(base + m * 16 + rc, nr - 1);
    offL[m] = sL[i]; offR[m] = sR[i];
  }
  f32x4 acc[5][4];
  #pragma unroll
  for (int g = 0; g < 5; g++)
    #pragma unroll
    for (int m = 0; m < 4; m++) acc[g][m] = (f32x4){0.f,0.f,0.f,0.f};

  int bswz = (rc & 7) << 3;
  const unsigned short* gb = WT + (size_t)(u0 + rc) * 1024 + lg * 8;

  bf16x8 a_cur[4], b_cur[3];
  #pragma unroll
  for (int m = 0; m < 4; m++) a_cur[m] = *(const bf16x8*)(HB + offL[m] + lg * 8);
  #pragma unroll
  for (int g = 0; g < 3; g++)
    b_cur[g] = *(const bf16x8*)(gb + (size_t)(g + 2) * (512 * 1024));

  #pragma unroll 4
  for (int j = 0; j < 32; ++j){
    bf16x8 a_nxt[4], b_nxt[3];
    if (j < 31){
      int kn = (j + 1) * 32 + lg * 8;
      #pragma unroll
      for (int m = 0; m < 4; m++){
        const unsigned short* ap = (j + 1 < 16) ? (HB + offL[m] + kn) : (HB + offR[m] + (kn - 512));
        a_nxt[m] = *(const bf16x8*)ap;
      }
      #pragma unroll
      for (int g = 0; g < 3; g++)
        b_nxt[g] = *(const bf16x8*)(gb + (size_t)(g + 2) * (512 * 1024) + (j + 1) * 32);
    }
    int k = j * 32 + lg * 8;
    #pragma unroll
    for (int g = 0; g < 2; g++){
      bf16x8 bb;
      if (LDSB) bb = *(const bf16x8*)&wlds[(size_t)(g * 16 + rc) * 1024 + (k ^ bswz)];
      else      bb = *(const bf16x8*)(gb + (size_t)g * (512 * 1024) + j * 32);
      #pragma unroll
      for (int m = 0; m < 4; m++)
        acc[g][m] = __builtin_amdgcn_mfma_f32_16x16x32_bf16(a_cur[m], bb, acc[g][m], 0, 0, 0);
    }
    #pragma unroll
    for (int g = 0; g < 3; g++){
      #pragma unroll
      for (int m = 0; m < 4; m++)
        acc[g + 2][m] = __builtin_amdgcn_mfma_f32_16x16x32_bf16(a_cur[m], b_cur[g], acc[g + 2][m], 0, 0, 0);
    }
    #pragma unroll
    for (int m = 0; m < 4; m++) a_cur[m] = a_nxt[m];
    #pragma unroll
    for (int g = 0; g < 3; g++) b_cur[g] = b_nxt[g];
  }
  // lane-local LSTM epilogue: C/D row = lg*4+q, col = rc
  int colu = u0 + rc;
  float bs[5];
  #pragma unroll
  for (int g = 0; g < 5; g++) bs[g] = b_red[g * Hn + colu];
  #pragma unroll
  for (int m = 0; m < 4; m++){
    #pragma unroll
    for (int q = 0; q < 4; q++){
      int i = base + m * 16 + lg * 4 + q;
      if (i < nr){
        int oL = sL[i], oR = sR[i], oD = dl[i];
        float gv = tanh_fast(acc[0][m][q] + bs[0]);
        float iv = sigm(acc[1][m][q] + bs[1]);
        float f1 = sigm(acc[2][m][q] + bs[2]);
        float f2 = sigm(acc[3][m][q] + bs[3]);
        float ov = sigm(acc[4][m][q] + bs[4]);
        float cl = __builtin_nontemporal_load(CF + oL + colu);
        float cr = __builtin_nontemporal_load(CF + oR + colu);
        float cv = gv * iv + f1 * cl + f2 * cr;
        float hv = ov * tanh_fast(cv);
        __builtin_nontemporal_store(cv, CF + oD + colu);
        HB[oD + colu] = f2bf(hv);
      }
    }
  }
}

// ---------------- small-level tile: 16 rows x 16 u, K split over 4 waves ----------------
static __device__ __forceinline__ void tile16(
    int u0, int t, int nr, const int* __restrict__ sL, const int* __restrict__ sR,
    const int* __restrict__ dl,
    unsigned short* __restrict__ HB, float* __restrict__ CF,
    const unsigned short* __restrict__ WT, const float* __restrict__ b_red,
    const unsigned short* __restrict__ wlds, float (*part)[2][16][20],
    int tid, int w, int rc, int lg)
{
  int base = t * 16;
  int i0 = min(base + rc, nr - 1);
  int offA = (w >= 2) ? sR[i0] : sL[i0];
  int k0 = w * 256;                       // this wave's K quarter (of 1024)
  int abase = (w >= 2) ? (k0 - 512) : k0; // child-local K offset
  const unsigned short* ap = HB + offA + abase + lg * 8;
  int bswz = (rc & 7) << 3;
  const unsigned short* gb = WT + (size_t)(u0 + rc) * 1024;

  f32x4 acc[5];
  #pragma unroll
  for (int g = 0; g < 5; g++) acc[g] = (f32x4){0.f,0.f,0.f,0.f};

  bf16x8 a_cur = *(const bf16x8*)ap;
  bf16x8 b_cur[3];
  #pragma unroll
  for (int g = 0; g < 3; g++)
    b_cur[g] = *(const bf16x8*)(gb + (size_t)(g + 2) * (512 * 1024) + k0 + lg * 8);

  #pragma unroll
  for (int j = 0; j < 8; ++j){
    bf16x8 a_nxt, b_nxt[3];
    if (j < 7){
      a_nxt = *(const bf16x8*)(ap + (j + 1) * 32);
      #pragma unroll
      for (int g = 0; g < 3; g++)
        b_nxt[g] = *(const bf16x8*)(gb + (size_t)(g + 2) * (512 * 1024) + k0 + (j + 1) * 32 + lg * 8);
    }
    int k = k0 + j * 32 + lg * 8;
    #pragma unroll
    for (int g = 0; g < 2; g++){
      bf16x8 bb = *(const bf16x8*)&wlds[(size_t)(g * 16 + rc) * 1024 + (k ^ bswz)];
      acc[g] = __builtin_amdgcn_mfma_f32_16x16x32_bf16(a_cur, bb, acc[g], 0, 0, 0);
    }
    #pragma unroll
    for (int g = 0; g < 3; g++)
      acc[g + 2] = __builtin_amdgcn_mfma_f32_16x16x32_bf16(a_cur, b_cur[g], acc[g + 2], 0, 0, 0);
    a_cur = a_nxt;
    #pragma unroll
    for (int g = 0; g < 3; g++) b_cur[g] = b_nxt[g];
  }
  // combine across waves, gate pairs (LDS [4][2][16][20])
  int er = tid >> 4, eu = tid & 15;
  float sg[5];
  #pragma unroll
  for (int r = 0; r < 3; ++r){
    int ng = (r < 2) ? 2 : 1;
    #pragma unroll
    for (int gi = 0; gi < 2; ++gi){
      if (gi < ng){
        int g = r * 2 + gi;
        #pragma unroll
        for (int q = 0; q < 4; q++) part[w][gi][lg * 4 + q][rc] = acc[g][q];
      }
    }
    __syncthreads();
    #pragma unroll
    for (int gi = 0; gi < 2; ++gi){
      if (gi < ng)
        sg[r * 2 + gi] = part[0][gi][er][eu] + part[1][gi][er][eu]
                       + part[2][gi][er][eu] + part[3][gi][er][eu];
    }
    __syncthreads();
  }
  int i = base + er;
  if (i < nr){
    int colu = u0 + eu;
    int oL = sL[i], oR = sR[i], oD = dl[i];
    float gv = tanh_fast(sg[0] + b_red[colu]);
    float iv = sigm(sg[1] + b_red[Hn + colu]);
    float f1 = sigm(sg[2] + b_red[2 * Hn + colu]);
    float f2 = sigm(sg[3] + b_red[3 * Hn + colu]);
    float ov = sigm(sg[4] + b_red[4 * Hn + colu]);
    float cl = __builtin_nontemporal_load(CF + oL + colu);
    float cr = __builtin_nontemporal_load(CF + oR + colu);
    float cv = gv * iv + f1 * cl + f2 * cr;
    float hv = ov * tanh_fast(cv);
    __builtin_nontemporal_store(cv, CF + oD + colu);
    HB[oD + colu] = f2bf(hv);
  }
  __syncthreads();
}

// ---------------- persistent XCD-sharded tree kernel ----------------
extern __shared__ char dynbuf[];

__global__ __launch_bounds__(256, 2) void tree_kernel(
    unsigned short* __restrict__ HB, float* __restrict__ CF,
    const unsigned short* __restrict__ WT, const float* __restrict__ b_red,
    const int* __restrict__ srcL, const int* __restrict__ srcR,
    const int* __restrict__ dstv, const int* __restrict__ cnt,
    const int* __restrict__ outsrc, float* __restrict__ out, int* bar){
  unsigned short* wlds = (unsigned short*)dynbuf;             // 64KB: gates 0-1
  float (*part)[2][16][20] = (float(*)[2][16][20])(dynbuf + WLDS_BYTES);
  int bid = blockIdx.x;
  int tid = threadIdx.x, w = tid >> 6, lane = tid & 63;
  int rc = lane & 15, lg = lane >> 4;

  int x = xcc_id();
  if (tid == 0){
    int r = __hip_atomic_fetch_add(&bar[OFF_CENSUS + x * FPAD], 1,
                                   __ATOMIC_RELAXED, __HIP_MEMORY_SCOPE_AGENT);
    __hip_atomic_store(&bar[OFF_RANK + bid * FPAD], r, __ATOMIC_RELAXED, __HIP_MEMORY_SCOPE_AGENT);
  }
  __syncthreads();
  int rank = min(__hip_atomic_load(&bar[OFF_RANK + bid * FPAD], __ATOMIC_RELAXED, __HIP_MEMORY_SCOPE_AGENT),
                 MAXRANK - 1);
  int ub = rank & 31;
  int u0 = ub * 16;

  // stage gates 0-1 of this u-block into LDS (XOR-swizzled k)
  for (int gg = tid; gg < 4096; gg += 256){
    int row = gg >> 7;                 // g*16 + u, 0..31
    int k = (gg & 127) * 8;
    int u = row & 15, g = row >> 4;
    bf16x8 v = *(const bf16x8*)(WT + (size_t)(g * 512 + u0 + u) * 1024 + k);
    int kx = k ^ ((u & 7) << 3);
    *(bf16x8*)&wlds[(size_t)row * 1024 + kx] = v;
  }
  __syncthreads();

  // global start barrier so census counts are final
  {
    int* sfl  = bar + OFF_SFLAG;
    int* sgen = bar + OFF_SGEN;
    if (bid == 0){
      for (int i = tid; i < NBLK; i += 256){
        if (i){
          int c = 0;
          while (__hip_atomic_load(&sfl[i * FPAD], __ATOMIC_RELAXED, __HIP_MEMORY_SCOPE_AGENT) == 0 && c < SPIN_CAP){
            __builtin_amdgcn_s_sleep(1); ++c;
          }
        }
      }
      __syncthreads();
      if (tid == 0) __hip_atomic_store(sgen, 1, __ATOMIC_RELAXED, __HIP_MEMORY_SCOPE_AGENT);
    } else {
      if (tid == 0){
        __hip_atomic_store(&sfl[bid * FPAD], 1, __ATOMIC_RELAXED, __HIP_MEMORY_SCOPE_AGENT);
        int c = 0;
        while (__hip_atomic_load(sgen, __ATOMIC_RELAXED, __HIP_MEMORY_SCOPE_AGENT) == 0 && c < SPIN_CAP){
          __builtin_amdgcn_s_sleep(2); ++c;
        }
      }
      __syncthreads();
    }
  }
  int nx = max(__hip_atomic_load(&bar[OFF_CENSUS + x * FPAD], __ATOMIC_RELAXED, __HIP_MEMORY_SCOPE_AGENT), 1);

  int maxlvl = cnt[NXCD * NLVL + x];
  int epoch = 1;
  for (int lvl = 1; lvl <= maxlvl; ++lvl, ++epoch){
    int nr = cnt[x * NLVL + lvl];
    const int* sL = srcL + (x * NLVL + lvl) * CAPX;
    const int* sR = srcR + (x * NLVL + lvl) * CAPX;
    const int* dl = dstv + (x * NLVL + lvl) * CAPX;
    if (nr > 0){
      if (nx >= 32){
        int nstr = (nx - 1 - ub) / 32 + 1;     // blocks sharing this ub
        int stripe = rank >> 5;
        if (nr >= 128){
          int ntl = (nr + 63) >> 6;
          for (int t = stripe * 4 + w; t < ntl; t += nstr * 4)
            tile64<true>(u0, t, nr, sL, sR, dl, HB, CF, WT, b_red, wlds, rc, lg);
        } else {
          int ntl16 = (nr + 15) >> 4;
          for (int t = stripe; t < ntl16; t += nstr)
            tile16(u0, t, nr, sL, sR, dl, HB, CF, WT, b_red, wlds, part, tid, w, rc, lg);
        }
      } else {
        // rare fallback: cover all 32 u-blocks from global
        int ntl = (nr + 63) >> 6;
        int nwv = nx * 4, wid = rank * 4 + w;
        int ntask = ntl * 32;
        for (int task = wid; task < ntask; task += nwv)
          tile64<false>((task / ntl) * 16, task % ntl, nr, sL, sR, dl, HB, CF, WT, b_red, wlds, rc, lg);
      }
    }
    xcd_barrier(bar, x, rank, nx, epoch);
  }

  // final gather for this XCD's 16 trees
  for (int j = rank; j < 16; j += min(nx, MAXRANK)){
    int b = x + 8 * j;
    int src = outsrc[b];
    out[b * Hn + tid]       = bf2f(HB[src + tid]);
    out[b * Hn + tid + 256] = bf2f(HB[src + tid + 256]);
  }
}

// ---------------- launch ----------------
extern "C" void kernel_launch(void* const* d_in, const int* in_sizes, int n_in,
                              void* d_out, int out_size, void* d_ws, size_t ws_size,
                              hipStream_t stream){
  (void)in_sizes; (void)n_in; (void)out_size; (void)ws_size;
  const float* sentence = (const float*)d_in[0];
  const int*   trans    = (const int*)d_in[1];
  const float* W_word   = (const float*)d_in[2];
  const float* b_word   = (const float*)d_in[3];
  const float* W_left   = (const float*)d_in[4];
  const float* W_right  = (const float*)d_in[5];
  const float* b_red    = (const float*)d_in[6];

  char* ws = (char*)d_ws;
  size_t off = 0;
  auto alloc = [&](size_t bytes) -> void* {
    void* p = ws + off;
    off += (bytes + 255) & ~((size_t)255);
    return p;
  };
  unsigned short* HB  = (unsigned short*)alloc((size_t)TOT_ROWS * Hn * 2);
  float*          CF  = (float*)alloc((size_t)TOT_ROWS * Hn * 4);
  unsigned short* WT  = (unsigned short*)alloc((size_t)2560 * 1024 * 2);
  unsigned short* SB  = (unsigned short*)alloc((size_t)LEAF_ROWS * En * 2);
  unsigned short* WwT = (unsigned short*)alloc((size_t)1024 * En * 2);
  int* srcL   = (int*)alloc((size_t)NXCD * NLVL * CAPX * 4);
  int* srcR   = (int*)alloc((size_t)NXCD * NLVL * CAPX * 4);
  int* dstv   = (int*)alloc((size_t)NXCD * NLVL * CAPX * 4);
  int* cnt    = (int*)alloc((size_t)(NXCD * NLVL + NXCD) * 4);
  int* outsrc = (int*)alloc((size_t)Bn * 4);
  int* bar    = (int*)alloc((size_t)BAR_INTS * 4);
  float* outp = (float*)d_out;

  hipFuncSetAttribute(reinterpret_cast<const void*>(tree_kernel),
                      hipFuncAttributeMaxDynamicSharedMemorySize, DYN_BYTES);

  cvt_vec4<<<(LEAF_ROWS * En / 4) / 256, 256, 0, stream>>>((const float4*)sentence, (ushort4*)SB, LEAF_ROWS * En / 4);
  transpose_cvt<<<dim3(1024 / 32, En / 32), dim3(32, 8), 0, stream>>>(W_word, WwT, 1024, En, 0);
  transpose_cvt<<<dim3(2560 / 32, Hn / 32), dim3(32, 8), 0, stream>>>(W_left, WT, 2560, 1024, 0);
  transpose_cvt<<<dim3(2560 / 32, Hn / 32), dim3(32, 8), 0, stream>>>(W_right, WT, 2560, 1024, 512);
  precompute_ctrl<<<1, 128, 0, stream>>>(trans, srcL, srcR, dstv, cnt, outsrc, bar);
  word_gemm<<<dim3(8, LEAF_ROWS / 64), 256, 0, stream>>>(SB, WwT, b_word, HB, CF);
  tree_kernel<<<NBLK, 256, DYN_BYTES, stream>>>(HB, CF, WT, b_red, srcL, srcR, dstv, cnt, outsrc, outp, bar);
}

// Round 12
// 597.403 us; speedup vs baseline: 3.0064x; 1.0030x over previous
//
#include <hip/hip_runtime.h>
#include <hip/hip_bf16.h>

// SPINN: word GEMM + XCD-sharded persistent TreeLSTM.
// r11: r10 + non-temporal CF traffic (C rows are read-once -> bypass L2 so the
// 3MB/XCD streamed gate set stays L2-resident) + B-prefetch for gates 2-4.
// Weights: gates 0-1 LDS-resident per u-block (64KB, XOR-swizzled); gates 2-4
// streamed from L2. 512 blocks = 2/CU, 2 blocks per u-block. Fence-free
// per-XCD barriers (r7-proven).
// B=128, L=64, E=512, H=512, T=127.

#define Bn 128
#define Ln 64
#define En 512
#define Hn 512
#define Tn 127
#define LEAF_ROWS (Bn*Ln)
#define NODE_ROWS (Bn*(Ln-1))
#define TOT_ROWS (LEAF_ROWS+NODE_ROWS)
#define NLVL 64
#define NXCD 8
#define CAPX 512                 // max rows per XCD-bin per level
#define NBLK 512                 // 2 blocks/CU
#define FPAD 16
#define MAXRANK 96
#define SPIN_CAP (1<<22)
#define WLDS_BYTES 65536         // 2 gates x 16u x 1024k x 2B
#define PART_BYTES (4*2*16*20*4) // [wave][gatepair][row][col+pad] f32
#define DYN_BYTES (WLDS_BYTES + PART_BYTES)

// barrier/census state layout (ints), zeroed by precompute_ctrl each call
#define OFF_CENSUS 0                              // NXCD*FPAD
#define OFF_RANK   (OFF_CENSUS + NXCD*FPAD)       // NBLK*FPAD
#define OFF_SFLAG  (OFF_RANK + NBLK*FPAD)         // NBLK*FPAD
#define OFF_SGEN   (OFF_SFLAG + NBLK*FPAD)        // FPAD
#define OFF_FX     (OFF_SGEN + FPAD)              // NXCD*MAXRANK*FPAD
#define OFF_GX     (OFF_FX + NXCD*MAXRANK*FPAD)   // NXCD*FPAD
#define BAR_INTS   (OFF_GX + NXCD*FPAD)

typedef __attribute__((ext_vector_type(8))) short bf16x8;
typedef __attribute__((ext_vector_type(4))) float f32x4;

static __device__ __forceinline__ float bf2f(unsigned short u){
  unsigned v = ((unsigned)u) << 16;
  float f; __builtin_memcpy(&f, &v, 4); return f;
}
static __device__ __forceinline__ unsigned short f2bf(float f){
  unsigned u; __builtin_memcpy(&u, &f, 4);
  u = u + 0x7FFFu + ((u >> 16) & 1u);   // round-nearest-even
  return (unsigned short)(u >> 16);
}
static __device__ __forceinline__ float sigm(float x){
  return 1.0f / (1.0f + __expf(-x));
}
static __device__ __forceinline__ float tanh_fast(float x){
  x = fminf(fmaxf(x, -15.0f), 15.0f);
  float t = __expf(2.0f * x);
  return (t - 1.0f) / (t + 1.0f);
}
static __device__ __forceinline__ int xcc_id(){
  unsigned v;
  asm volatile("s_getreg_b32 %0, hwreg(HW_REG_XCC_ID)" : "=s"(v));
  return (int)(v & 7);
}

// Per-XCD fence-free barrier (r7-proven).
static __device__ __forceinline__ void xcd_barrier(int* bar, int x, int rank, int nx, int epoch){
  __syncthreads();
  int* fx = bar + OFF_FX + x * MAXRANK * FPAD;
  int* gx = bar + OFF_GX + x * FPAD;
  int nxl = min(nx, MAXRANK);
  if (rank == 0){
    for (int i = threadIdx.x + 1; i < nxl; i += 256){
      int c = 0;
      while (__hip_atomic_load(&fx[i * FPAD], __ATOMIC_RELAXED, __HIP_MEMORY_SCOPE_AGENT) < epoch && c < SPIN_CAP){
        __builtin_amdgcn_s_sleep(1); ++c;
      }
    }
    __syncthreads();
    if (threadIdx.x == 0)
      __hip_atomic_store(gx, epoch, __ATOMIC_RELAXED, __HIP_MEMORY_SCOPE_AGENT);
  } else {
    if (threadIdx.x == 0){
      __hip_atomic_store(&fx[rank * FPAD], epoch, __ATOMIC_RELAXED, __HIP_MEMORY_SCOPE_AGENT);
      int c = 0;
      while (__hip_atomic_load(gx, __ATOMIC_RELAXED, __HIP_MEMORY_SCOPE_AGENT) < epoch && c < SPIN_CAP){
        __builtin_amdgcn_s_sleep(2); ++c;
      }
    }
    __syncthreads();
  }
  asm volatile("" ::: "memory");
}

// ---------------- convert / transpose helpers ----------------

__global__ void cvt_vec4(const float4* __restrict__ x, ushort4* __restrict__ y, int n4){
  int i = blockIdx.x * 256 + threadIdx.x;
  if (i < n4){
    float4 v = x[i];
    ushort4 o;
    o.x = f2bf(v.x); o.y = f2bf(v.y); o.z = f2bf(v.z); o.w = f2bf(v.w);
    y[i] = o;
  }
}

__global__ void transpose_cvt(const float* __restrict__ src, unsigned short* __restrict__ dstT,
                              int CS, int DS, int koff){
  __shared__ float tile[32][33];
  int c0 = blockIdx.x * 32, r0 = blockIdx.y * 32;
  int tx = threadIdx.x, ty = threadIdx.y;
  for (int i = ty; i < 32; i += 8) tile[i][tx] = src[(size_t)(r0 + i) * CS + c0 + tx];
  __syncthreads();
  for (int i = ty; i < 32; i += 8)
    dstT[(size_t)(c0 + i) * DS + koff + r0 + tx] = f2bf(tile[tx][i]);
}

// ---------------- control precompute ----------------
__global__ void precompute_ctrl(const int* __restrict__ trans,
                                int* __restrict__ srcL, int* __restrict__ srcR,
                                int* __restrict__ dstv, int* __restrict__ cnt,
                                int* __restrict__ outsrc, int* __restrict__ bar){
  __shared__ int stk[Bn][Ln + 1];
  __shared__ int scnt[NXCD * NLVL];
  __shared__ int smaxl[NXCD];
  int b = threadIdx.x;
  for (int i = b; i < NXCD * NLVL; i += 128) scnt[i] = 0;
  if (b < NXCD) smaxl[b] = 0;
  for (int i = b; i < BAR_INTS; i += 128) bar[i] = 0;
  __syncthreads();
  int x = b & 7;
  int sp = 0, bp = 0, nodecnt = 0;
  int act_next = trans[b * Tn];
  for (int t = 0; t < Tn; t++){
    int act = act_next;
    if (t + 1 < Tn) act_next = trans[b * Tn + t + 1];
    int ops = Tn - t;
    if (sp > ops) act = 2;                       // forced REDUCE (matches ref)
    if (act == 2){
      int R = stk[b][sp - 1], L = stk[b][sp - 2];
      int lvl = max(R >> 20, L >> 20) + 1;
      int slot = atomicAdd(&scnt[x * NLVL + lvl], 1);
      int base = (x * NLVL + lvl) * CAPX + slot;
      srcL[base] = (L & 0xFFFFF) * Hn;
      srcR[base] = (R & 0xFFFFF) * Hn;
      int noderow = LEAF_ROWS + b * (Ln - 1) + nodecnt;
      dstv[base] = noderow * Hn;
      stk[b][sp - 2] = noderow | (lvl << 20);
      sp -= 1; nodecnt++;
    } else {
      stk[b][sp] = b * Ln + min(bp, Ln - 1);
      sp += 1; bp += 1;
    }
  }
  int root = stk[b][max(sp - 1, 0)];
  outsrc[b] = (root & 0xFFFFF) * Hn;
  atomicMax(&smaxl[x], root >> 20);
  __syncthreads();
  for (int i = b; i < NXCD * NLVL; i += 128) cnt[i] = scnt[i];
  if (b < NXCD) cnt[NXCD * NLVL + b] = smaxl[b];
}

// ---------------- word GEMM ----------------
__global__ __launch_bounds__(256) void word_gemm(
    const unsigned short* __restrict__ SB, const unsigned short* __restrict__ WwT,
    const float* __restrict__ b_word,
    unsigned short* __restrict__ HB, float* __restrict__ CF){
  int nt = blockIdx.x;
  int mt = blockIdx.y;
  int tid = threadIdx.x, w = tid >> 6, lane = tid & 63;
  int wm = w >> 1, wn = w & 1;
  int rc = lane & 15, lg = lane >> 4;
  const unsigned short* ap0 = SB + (size_t)(mt * 64 + wm * 32 + rc) * En + lg * 8;
  const unsigned short* ap1 = ap0 + (size_t)16 * En;
  const unsigned short* bp0 = WwT + (size_t)(nt * 128 + wn * 64 + rc) * En + lg * 8;
  f32x4 acc[2][4];
  #pragma unroll
  for (int h = 0; h < 2; h++)
    #pragma unroll
    for (int nb = 0; nb < 4; nb++) acc[h][nb] = (f32x4){0.f,0.f,0.f,0.f};
  #pragma unroll 4
  for (int k0 = 0; k0 < En; k0 += 32){
    bf16x8 a0 = *(const bf16x8*)(ap0 + k0);
    bf16x8 a1 = *(const bf16x8*)(ap1 + k0);
    #pragma unroll
    for (int nb = 0; nb < 4; nb++){
      bf16x8 bb = *(const bf16x8*)(bp0 + (size_t)nb * 16 * En + k0);
      acc[0][nb] = __builtin_amdgcn_mfma_f32_16x16x32_bf16(a0, bb, acc[0][nb], 0, 0, 0);
      acc[1][nb] = __builtin_amdgcn_mfma_f32_16x16x32_bf16(a1, bb, acc[1][nb], 0, 0, 0);
    }
  }
  #pragma unroll
  for (int nb = 0; nb < 4; nb++){
    int col = nt * 128 + wn * 64 + nb * 16 + rc;
    float bw = b_word[col];
    #pragma unroll
    for (int h = 0; h < 2; h++){
      #pragma unroll
      for (int q = 0; q < 4; q++){
        int row = mt * 64 + wm * 32 + h * 16 + lg * 4 + q;
        float v = acc[h][nb][q] + bw;
        if (col < Hn) HB[(size_t)row * Hn + col] = f2bf(v);
        else          CF[(size_t)row * Hn + (col - Hn)] = v;
      }
    }
  }
}

// ---------------- big-level tile: 64 rows x 16 u, full K per wave ----------------
// Gates 0-1 from LDS (swizzled); gates 2-4 global with 1-step register prefetch
// (as is A). CF accesses non-temporal (read-once data; keep weights in L2).
template<bool LDSB>
static __device__ __forceinline__ void tile64(
    int u0, int t, int nr, const int* __restrict__ sL, const int* __restrict__ sR,
    const int* __restrict__ dl,
    unsigned short* __restrict__ HB, float* __restrict__ CF,
    const unsigned short* __restrict__ WT, const float* __restrict__ b_red,
    const unsigned short* __restrict__ wlds, int rc, int lg)
{
  int base = t * 64;
  int offL[4], offR[4];
  #pragma unroll
  for (int m = 0; m < 4; m++){
    int i = min(base + m * 16 + rc, nr - 1);
    offL[m] = sL[i]; offR[m] = sR[i];
  }
  f32x4 acc[5][4];
  #pragma unroll
  for (int g = 0; g < 5; g++)
    #pragma unroll
    for (int m = 0; m < 4; m++) acc[g][m] = (f32x4){0.f,0.f,0.f,0.f};

  int bswz = (rc & 7) << 3;
  const unsigned short* gb = WT + (size_t)(u0 + rc) * 1024 + lg * 8;

  bf16x8 a_cur[4], b_cur[3];
  #pragma unroll
  for (int m = 0; m < 4; m++) a_cur[m] = *(const bf16x8*)(HB + offL[m] + lg * 8);
  #pragma unroll
  for (int g = 0; g < 3; g++)
    b_cur[g] = *(const bf16x8*)(gb + (size_t)(g + 2) * (512 * 1024));

  #pragma unroll 4
  for (int j = 0; j < 32; ++j){
    bf16x8 a_nxt[4], b_nxt[3];
    if (j < 31){
      int kn = (j + 1) * 32 + lg * 8;
      #pragma unroll
      for (int m = 0; m < 4; m++){
        const unsigned short* ap = (j + 1 < 16) ? (HB + offL[m] + kn) : (HB + offR[m] + (kn - 512));
        a_nxt[m] = *(const bf16x8*)ap;
      }
      #pragma unroll
      for (int g = 0; g < 3; g++)
        b_nxt[g] = *(const bf16x8*)(gb + (size_t)(g + 2) * (512 * 1024) + (j + 1) * 32);
    }
    int k = j * 32 + lg * 8;
    #pragma unroll
    for (int g = 0; g < 2; g++){
      bf16x8 bb;
      if (LDSB) bb = *(const bf16x8*)&wlds[(size_t)(g * 16 + rc) * 1024 + (k ^ bswz)];
      else      bb = *(const bf16x8*)(gb + (size_t)g * (512 * 1024) + j * 32);
      #pragma unroll
      for (int m = 0; m < 4; m++)
        acc[g][m] = __builtin_amdgcn_mfma_f32_16x16x32_bf16(a_cur[m], bb, acc[g][m], 0, 0, 0);
    }
    #pragma unroll
    for (int g = 0; g < 3; g++){
      #pragma unroll
      for (int m = 0; m < 4; m++)
        acc[g + 2][m] = __builtin_amdgcn_mfma_f32_16x16x32_bf16(a_cur[m], b_cur[g], acc[g + 2][m], 0, 0, 0);
    }
    #pragma unroll
    for (int m = 0; m < 4; m++) a_cur[m] = a_nxt[m];
    #pragma unroll
    for (int g = 0; g < 3; g++) b_cur[g] = b_nxt[g];
  }
  // lane-local LSTM epilogue: C/D row = lg*4+q, col = rc
  int colu = u0 + rc;
  float bs[5];
  #pragma unroll
  for (int g = 0; g < 5; g++) bs[g] = b_red[g * Hn + colu];
  #pragma unroll
  for (int m = 0; m < 4; m++){
    #pragma unroll
    for (int q = 0; q < 4; q++){
      int i = base + m * 16 + lg * 4 + q;
      if (i < nr){
        int oL = sL[i], oR = sR[i], oD = dl[i];
        float gv = tanh_fast(acc[0][m][q] + bs[0]);
        float iv = sigm(acc[1][m][q] + bs[1]);
        float f1 = sigm(acc[2][m][q] + bs[2]);
        float f2 = sigm(acc[3][m][q] + bs[3]);
        float ov = sigm(acc[4][m][q] + bs[4]);
        float cl = __builtin_nontemporal_load(CF + oL + colu);
        float cr = __builtin_nontemporal_load(CF + oR + colu);
        float cv = gv * iv + f1 * cl + f2 * cr;
        float hv = ov * tanh_fast(cv);
        __builtin_nontemporal_store(cv, CF + oD + colu);
        HB[oD + colu] = f2bf(hv);
      }
    }
  }
}

// ---------------- small-level tile: 16 rows x 16 u, K split over 4 waves ----------------
static __device__ __forceinline__ void tile16(
    int u0, int t, int nr, const int* __restrict__ sL, const int* __restrict__ sR,
    const int* __restrict__ dl,
    unsigned short* __restrict__ HB, float* __restrict__ CF,
    const unsigned short* __restrict__ WT, const float* __restrict__ b_red,
    const unsigned short* __restrict__ wlds, float (*part)[2][16][20],
    int tid, int w, int rc, int lg)
{
  int base = t * 16;
  int i0 = min(base + rc, nr - 1);
  int offA = (w >= 2) ? sR[i0] : sL[i0];
  int k0 = w * 256;                       // this wave's K quarter (of 1024)
  int abase = (w >= 2) ? (k0 - 512) : k0; // child-local K offset
  const unsigned short* ap = HB + offA + abase + lg * 8;
  int bswz = (rc & 7) << 3;
  const unsigned short* gb = WT + (size_t)(u0 + rc) * 1024;

  f32x4 acc[5];
  #pragma unroll
  for (int g = 0; g < 5; g++) acc[g] = (f32x4){0.f,0.f,0.f,0.f};

  bf16x8 a_cur = *(const bf16x8*)ap;
  bf16x8 b_cur[3];
  #pragma unroll
  for (int g = 0; g < 3; g++)
    b_cur[g] = *(const bf16x8*)(gb + (size_t)(g + 2) * (512 * 1024) + k0 + lg * 8);

  #pragma unroll
  for (int j = 0; j < 8; ++j){
    bf16x8 a_nxt, b_nxt[3];
    if (j < 7){
      a_nxt = *(const bf16x8*)(ap + (j + 1) * 32);
      #pragma unroll
      for (int g = 0; g < 3; g++)
        b_nxt[g] = *(const bf16x8*)(gb + (size_t)(g + 2) * (512 * 1024) + k0 + (j + 1) * 32 + lg * 8);
    }
    int k = k0 + j * 32 + lg * 8;
    #pragma unroll
    for (int g = 0; g < 2; g++){
      bf16x8 bb = *(const bf16x8*)&wlds[(size_t)(g * 16 + rc) * 1024 + (k ^ bswz)];
      acc[g] = __builtin_amdgcn_mfma_f32_16x16x32_bf16(a_cur, bb, acc[g], 0, 0, 0);
    }
    #pragma unroll
    for (int g = 0; g < 3; g++)
      acc[g + 2] = __builtin_amdgcn_mfma_f32_16x16x32_bf16(a_cur, b_cur[g], acc[g + 2], 0, 0, 0);
    a_cur = a_nxt;
    #pragma unroll
    for (int g = 0; g < 3; g++) b_cur[g] = b_nxt[g];
  }
  // combine across waves, gate pairs (LDS [4][2][16][20])
  int er = tid >> 4, eu = tid & 15;
  float sg[5];
  #pragma unroll
  for (int r = 0; r < 3; ++r){
    int ng = (r < 2) ? 2 : 1;
    #pragma unroll
    for (int gi = 0; gi < 2; ++gi){
      if (gi < ng){
        int g = r * 2 + gi;
        #pragma unroll
        for (int q = 0; q < 4; q++) part[w][gi][lg * 4 + q][rc] = acc[g][q];
      }
    }
    __syncthreads();
    #pragma unroll
    for (int gi = 0; gi < 2; ++gi){
      if (gi < ng)
        sg[r * 2 + gi] = part[0][gi][er][eu] + part[1][gi][er][eu]
                       + part[2][gi][er][eu] + part[3][gi][er][eu];
    }
    __syncthreads();
  }
  int i = base + er;
  if (i < nr){
    int colu = u0 + eu;
    int oL = sL[i], oR = sR[i], oD = dl[i];
    float gv = tanh_fast(sg[0] + b_red[colu]);
    float iv = sigm(sg[1] + b_red[Hn + colu]);
    float f1 = sigm(sg[2] + b_red[2 * Hn + colu]);
    float f2 = sigm(sg[3] + b_red[3 * Hn + colu]);
    float ov = sigm(sg[4] + b_red[4 * Hn + colu]);
    float cl = __builtin_nontemporal_load(CF + oL + colu);
    float cr = __builtin_nontemporal_load(CF + oR + colu);
    float cv = gv * iv + f1 * cl + f2 * cr;
    float hv = ov * tanh_fast(cv);
    __builtin_nontemporal_store(cv, CF + oD + colu);
    HB[oD + colu] = f2bf(hv);
  }
  __syncthreads();
}

// ---------------- persistent XCD-sharded tree kernel ----------------
extern __shared__ char dynbuf[];

__global__ __launch_bounds__(256, 2) void tree_kernel(
    unsigned short* __restrict__ HB, float* __restrict__ CF,
    const unsigned short* __restrict__ WT, const float* __restrict__ b_red,
    const int* __restrict__ srcL, const int* __restrict__ srcR,
    const int* __restrict__ dstv, const int* __restrict__ cnt,
    const int* __restrict__ outsrc, float* __restrict__ out, int* bar){
  unsigned short* wlds = (unsigned short*)dynbuf;             // 64KB: gates 0-1
  float (*part)[2][16][20] = (float(*)[2][16][20])(dynbuf + WLDS_BYTES);
  int bid = blockIdx.x;
  int tid = threadIdx.x, w = tid >> 6, lane = tid & 63;
  int rc = lane & 15, lg = lane >> 4;

  int x = xcc_id();
  if (tid == 0){
    int r = __hip_atomic_fetch_add(&bar[OFF_CENSUS + x * FPAD], 1,
                                   __ATOMIC_RELAXED, __HIP_MEMORY_SCOPE_AGENT);
    __hip_atomic_store(&bar[OFF_RANK + bid * FPAD], r, __ATOMIC_RELAXED, __HIP_MEMORY_SCOPE_AGENT);
  }
  __syncthreads();
  int rank = min(__hip_atomic_load(&bar[OFF_RANK + bid * FPAD], __ATOMIC_RELAXED, __HIP_MEMORY_SCOPE_AGENT),
                 MAXRANK - 1);
  int ub = rank & 31;
  int u0 = ub * 16;

  // stage gates 0-1 of this u-block into LDS (XOR-swizzled k)
  for (int gg = tid; gg < 4096; gg += 256){
    int row = gg >> 7;                 // g*16 + u, 0..31
    int k = (gg & 127) * 8;
    int u = row & 15, g = row >> 4;
    bf16x8 v = *(const bf16x8*)(WT + (size_t)(g * 512 + u0 + u) * 1024 + k);
    int kx = k ^ ((u & 7) << 3);
    *(bf16x8*)&wlds[(size_t)row * 1024 + kx] = v;
  }
  __syncthreads();

  // global start barrier so census counts are final
  {
    int* sfl  = bar + OFF_SFLAG;
    int* sgen = bar + OFF_SGEN;
    if (bid == 0){
      for (int i = tid; i < NBLK; i += 256){
        if (i){
          int c = 0;
          while (__hip_atomic_load(&sfl[i * FPAD], __ATOMIC_RELAXED, __HIP_MEMORY_SCOPE_AGENT) == 0 && c < SPIN_CAP){
            __builtin_amdgcn_s_sleep(1); ++c;
          }
        }
      }
      __syncthreads();
      if (tid == 0) __hip_atomic_store(sgen, 1, __ATOMIC_RELAXED, __HIP_MEMORY_SCOPE_AGENT);
    } else {
      if (tid == 0){
        __hip_atomic_store(&sfl[bid * FPAD], 1, __ATOMIC_RELAXED, __HIP_MEMORY_SCOPE_AGENT);
        int c = 0;
        while (__hip_atomic_load(sgen, __ATOMIC_RELAXED, __HIP_MEMORY_SCOPE_AGENT) == 0 && c < SPIN_CAP){
          __builtin_amdgcn_s_sleep(2); ++c;
        }
      }
      __syncthreads();
    }
  }
  int nx = max(__hip_atomic_load(&bar[OFF_CENSUS + x * FPAD], __ATOMIC_RELAXED, __HIP_MEMORY_SCOPE_AGENT), 1);

  int maxlvl = cnt[NXCD * NLVL + x];
  int epoch = 1;
  for (int lvl = 1; lvl <= maxlvl; ++lvl, ++epoch){
    int nr = cnt[x * NLVL + lvl];
    const int* sL = srcL + (x * NLVL + lvl) * CAPX;
    const int* sR = srcR + (x * NLVL + lvl) * CAPX;
    const int* dl = dstv + (x * NLVL + lvl) * CAPX;
    if (nr > 0){
      if (nx >= 32){
        int nstr = (nx - 1 - ub) / 32 + 1;     // blocks sharing this ub
        int stripe = rank >> 5;
        if (nr >= 128){
          int ntl = (nr + 63) >> 6;
          for (int t = stripe * 4 + w; t < ntl; t += nstr * 4)
            tile64<true>(u0, t, nr, sL, sR, dl, HB, CF, WT, b_red, wlds, rc, lg);
        } else {
          int ntl16 = (nr + 15) >> 4;
          for (int t = stripe; t < ntl16; t += nstr)
            tile16(u0, t, nr, sL, sR, dl, HB, CF, WT, b_red, wlds, part, tid, w, rc, lg);
        }
      } else {
        // rare fallback: cover all 32 u-blocks from global
        int ntl = (nr + 63) >> 6;
        int nwv = nx * 4, wid = rank * 4 + w;
        int ntask = ntl * 32;
        for (int task = wid; task < ntask; task += nwv)
          tile64<false>((task / ntl) * 16, task % ntl, nr, sL, sR, dl, HB, CF, WT, b_red, wlds, rc, lg);
      }
    }
    xcd_barrier(bar, x, rank, nx, epoch);
  }

  // final gather for this XCD's 16 trees
  for (int j = rank; j < 16; j += min(nx, MAXRANK)){
    int b = x + 8 * j;
    int src = outsrc[b];
    out[b * Hn + tid]       = bf2f(HB[src + tid]);
    out[b * Hn + tid + 256] = bf2f(HB[src + tid + 256]);
  }
}

// ---------------- launch ----------------
extern "C" void kernel_launch(void* const* d_in, const int* in_sizes, int n_in,
                              void* d_out, int out_size, void* d_ws, size_t ws_size,
                              hipStream_t stream){
  (void)in_sizes; (void)n_in; (void)out_size; (void)ws_size;
  const float* sentence = (const float*)d_in[0];
  const int*   trans    = (const int*)d_in[1];
  const float* W_word   = (const float*)d_in[2];
  const float* b_word   = (const float*)d_in[3];
  const float* W_left   = (const float*)d_in[4];
  const float* W_right  = (const float*)d_in[5];
  const float* b_red    = (const float*)d_in[6];

  char* ws = (char*)d_ws;
  size_t off = 0;
  auto alloc = [&](size_t bytes) -> void* {
    void* p = ws + off;
    off += (bytes + 255) & ~((size_t)255);
    return p;
  };
  unsigned short* HB  = (unsigned short*)alloc((size_t)TOT_ROWS * Hn * 2);
  float*          CF  = (float*)alloc((size_t)TOT_ROWS * Hn * 4);
  unsigned short* WT  = (unsigned short*)alloc((size_t)2560 * 1024 * 2);
  unsigned short* SB  = (unsigned short*)alloc((size_t)LEAF_ROWS * En * 2);
  unsigned short* WwT = (unsigned short*)alloc((size_t)1024 * En * 2);
  int* srcL   = (int*)alloc((size_t)NXCD * NLVL * CAPX * 4);
  int* srcR   = (int*)alloc((size_t)NXCD * NLVL * CAPX * 4);
  int* dstv   = (int*)alloc((size_t)NXCD * NLVL * CAPX * 4);
  int* cnt    = (int*)alloc((size_t)(NXCD * NLVL + NXCD) * 4);
  int* outsrc = (int*)alloc((size_t)Bn * 4);
  int* bar    = (int*)alloc((size_t)BAR_INTS * 4);
  float* outp = (float*)d_out;

  hipFuncSetAttribute(reinterpret_cast<const void*>(tree_kernel),
                      hipFuncAttributeMaxDynamicSharedMemorySize, DYN_BYTES);

  cvt_vec4<<<(LEAF_ROWS * En / 4) / 256, 256, 0, stream>>>((const float4*)sentence, (ushort4*)SB, LEAF_ROWS * En / 4);
  transpose_cvt<<<dim3(1024 / 32, En / 32), dim3(32, 8), 0, stream>>>(W_word, WwT, 1024, En, 0);
  transpose_cvt<<<dim3(2560 / 32, Hn / 32), dim3(32, 8), 0, stream>>>(W_left, WT, 2560, 1024, 0);
  transpose_cvt<<<dim3(2560 / 32, Hn / 32), dim3(32, 8), 0, stream>>>(W_right, WT, 2560, 1024, 512);
  precompute_ctrl<<<1, 128, 0, stream>>>(trans, srcL, srcR, dstv, cnt, outsrc, bar);
  word_gemm<<<dim3(8, LEAF_ROWS / 64), 256, 0, stream>>>(SB, WwT, b_word, HB, CF);
  tree_kernel<<<NBLK, 256, DYN_BYTES, stream>>>(HB, CF, WT, b_red, srcL, srcR, dstv, cnt, outsrc, outp, bar);
}